// Round 1
// baseline (1021.359 us; speedup 1.0000x reference)
//
#include <hip/hip_runtime.h>
#include <math.h>

#define EPS_F 1e-15f
#define NRBF 20
#define CUTOFF_F 5.0f
#define PI_F 3.14159265358979323846f

typedef unsigned short u16;
typedef _Float16 f16;
typedef f16 f16x8 __attribute__((ext_vector_type(8)));
typedef f16 f16x4 __attribute__((ext_vector_type(4)));
typedef float floatx4 __attribute__((ext_vector_type(4)));

__device__ __forceinline__ float silu_f(float x) { return x / (1.0f + expf(-x)); }

// ---------------- counting sort: histogram + scan ----------------
__global__ __launch_bounds__(256) void hist_kernel(
    const int* __restrict__ nbr, int* __restrict__ hist, int E)
{
  int e = blockIdx.x * 256 + threadIdx.x;
  if (e >= E) return;
  atomicAdd(hist + nbr[2 * e], 1);
}

// single-block exclusive scan, wave-shfl based (few barriers)
__global__ __launch_bounds__(1024) void scan_kernel(
    const int* __restrict__ hist, int* __restrict__ start,
    int* __restrict__ cursor, int N)
{
  __shared__ int wsum[16];
  __shared__ int carry_s;
  int tid = threadIdx.x;
  int lane = tid & 63, wid = tid >> 6;
  if (tid == 0) carry_s = 0;
  __syncthreads();
  for (int base = 0; base < N; base += 1024) {
    int x = (base + tid < N) ? hist[base + tid] : 0;
    int v = x;
#pragma unroll
    for (int o = 1; o < 64; o <<= 1) {
      int t2 = __shfl_up(v, o, 64);
      if (lane >= o) v += t2;
    }
    if (lane == 63) wsum[wid] = v;
    __syncthreads();
    if (tid < 16) {
      int w = wsum[tid];
#pragma unroll
      for (int o = 1; o < 16; o <<= 1) {
        int t2 = __shfl_up(w, o, 64);
        if (tid >= o) w += t2;
      }
      wsum[tid] = w;
    }
    __syncthreads();
    int wbase = (wid == 0) ? 0 : wsum[wid - 1];
    int incl = v + wbase;
    int carry = carry_s;
    if (base + tid < N) {
      int ex = carry + incl - x;
      start[base + tid] = ex;
      cursor[base + tid] = ex;
    }
    __syncthreads();
    if (tid == 1023) carry_s = carry + incl;
    __syncthreads();
  }
  if (tid == 0) start[N] = carry_s;
}

// ---------------- scatter edge IDs ----------------
__global__ __launch_bounds__(256) void scatter_id_kernel(
    const int* __restrict__ nbr, int* __restrict__ cursor,
    int* __restrict__ order, int E)
{
  int e = blockIdx.x * 256 + threadIdx.x;
  if (e >= E) return;
  int pos = atomicAdd(cursor + nbr[2 * e], 1);
  order[pos] = e;
}

// ---------------- canonicalize: wave rank-sort of each atom's segment ----------------
__global__ __launch_bounds__(256) void segsort_kernel(
    int* __restrict__ order, const int* __restrict__ start, int N)
{
  int wi = blockIdx.x * 4 + (threadIdx.x >> 6);
  int lane = threadIdx.x & 63;
  if (wi >= N) return;
  int s0 = start[wi], s1 = start[wi + 1];
  int len = s1 - s0;
  if (len <= 1) return;
  if (len <= 64) {
    int id = (lane < len) ? order[s0 + lane] : 0x7FFFFFFF;
    int rank = 0;
#pragma unroll
    for (int k = 0; k < 64; ++k) {
      int other = __shfl(id, k, 64);
      rank += (other < id) ? 1 : 0;
    }
    if (lane < len) order[s0 + rank] = id;
  } else if (lane == 0) {
    for (int a = s0 + 1; a < s1; ++a) {
      int key = order[a];
      int b = a - 1;
      while (b >= s0 && order[b] > key) { order[b + 1] = order[b]; --b; }
      order[b + 1] = key;
    }
  }
}

// ---------------- geometry gather-fill (deterministic) ----------------
// rbf_h row layout (32 f16): slots 0..19 = sin(k_n d)/d * env   (env pre-folded!)
//                            slot  20    = env
//                            slots 21..31 = 0
// This makes w_s = rbfE @ [dist_w ; dist_b] with no separate env array.
__global__ __launch_bounds__(256) void geom_fill_kernel(
    const int* __restrict__ order, const int* __restrict__ nbr,
    const float* __restrict__ xyz, int* __restrict__ nbrj_s,
    float* __restrict__ unit_s, f16* __restrict__ rbf_h, int E)
{
  int p = blockIdx.x * 256 + threadIdx.x;
  if (p >= E) return;
  int e = order[p];
  int i = nbr[2 * e], j = nbr[2 * e + 1];
  float dx = xyz[3 * j + 0] - xyz[3 * i + 0];
  float dy = xyz[3 * j + 1] - xyz[3 * i + 1];
  float dz = xyz[3 * j + 2] - xyz[3 * i + 2];
  float d2 = dx * dx + dy * dy + dz * dz + 3.0f * EPS_F;  // ref adds EPS per comp
  float d = sqrtf(d2);
  float inv_d = 1.0f / d;
  nbrj_s[p] = j;
  unit_s[3 * p + 0] = dx * inv_d;
  unit_s[3 * p + 1] = dy * inv_d;
  unit_s[3 * p + 2] = dz * inv_d;
  float x = d * (PI_F / CUTOFF_F);
  float s1, c1;
  __sincosf(x, &s1, &c1);
  float envv = (d < CUTOFF_F) ? 0.5f * (c1 + 1.0f) : 0.0f;
  f16 tmp[32];
  float two_c = 2.0f * c1;
  float env_inv_d = envv * inv_d;
  float sp = 0.0f, sn = s1;           // Chebyshev recurrence for sin(n*x)
  tmp[0] = (f16)(sn * env_inv_d);
#pragma unroll
  for (int n = 1; n < NRBF; ++n) {
    float nx = two_c * sn - sp;
    sp = sn; sn = nx;
    tmp[n] = (f16)(sn * env_inv_d);
  }
  tmp[NRBF] = (f16)envv;
#pragma unroll
  for (int n = NRBF + 1; n < 32; ++n) tmp[n] = (f16)0.0f;
#pragma unroll
  for (int g = 0; g < 4; ++g)
    *(f16x8*)(rbf_h + (size_t)p * 32 + g * 8) = *(f16x8*)&tmp[g * 8];
}

// ---------------- s = embed[z] (fp32 + f16 mirror) ----------------
__global__ __launch_bounds__(256) void embed_kernel(
    const int* __restrict__ z, const float* __restrict__ embed,
    float* __restrict__ s, f16* __restrict__ s_h, int N)
{
  int idx = blockIdx.x * 256 + threadIdx.x;
  if (idx >= N * 128) return;
  int n = idx >> 7, f = idx & 127;
  float x = embed[z[n] * 128 + f];
  s[idx] = x;
  s_h[idx] = (f16)x;
}

__global__ __launch_bounds__(256) void w1t_kernel(
    const float* __restrict__ w1, f16* __restrict__ w1t)
{
  int idx = blockIdx.x * 256 + threadIdx.x;
  if (idx >= 64 * 128) return;
  int n = idx >> 7, k = idx & 127;
  w1t[idx] = (f16)w1[(size_t)k * 64 + n];
}

// ---------------- f16 MFMA GEMM ----------------
template <bool SILU, int OUT, bool AH>
__global__ __launch_bounds__(256) void gemm_kernel(
    const void* __restrict__ Ap, const float* __restrict__ W,
    const float* __restrict__ bias, const float* __restrict__ rowscale,
    void* __restrict__ Cout, int M, int N, int K)
{
  __shared__ f16 As[64][40];
  __shared__ f16 Bs[64][40];
  int t = threadIdx.x;
  int wave = t >> 6, lane = t & 63;
  int rw = wave & 1, cw = wave >> 1;
  int lr = lane & 15, quad = lane >> 4;
  int row0 = blockIdx.x * 64, col0 = blockIdx.y * 64;
  floatx4 acc[2][2] = {};
  for (int k0 = 0; k0 < K; k0 += 32) {
    if (AH) {
      const f16* A = (const f16*)Ap;
      int sm = t >> 2, sk = (t & 3) * 8;
      f16x8 av;
      if (row0 + sm < M) av = *(const f16x8*)(A + (size_t)(row0 + sm) * K + k0 + sk);
      else { for (int q = 0; q < 8; ++q) av[q] = (f16)0.0f; }
      *(f16x8*)&As[sm][sk] = av;
    } else {
      const float* A = (const float*)Ap;
#pragma unroll
      for (int u0 = 0; u0 < 2; ++u0) {
        int u = t + u0 * 256;
        int m = u >> 3, c4 = (u & 7) * 4;
        float4 av = make_float4(0.f, 0.f, 0.f, 0.f);
        if (row0 + m < M) av = *(const float4*)(A + (size_t)(row0 + m) * K + k0 + c4);
        f16x4 hv;
        hv[0] = (f16)av.x; hv[1] = (f16)av.y; hv[2] = (f16)av.z; hv[3] = (f16)av.w;
        *(f16x4*)&As[m][c4] = hv;
      }
    }
#pragma unroll
    for (int u0 = 0; u0 < 2; ++u0) {
      int u = t + u0 * 256;
      int k = u >> 4, n4 = (u & 15) * 4;
      float4 wv = *(const float4*)(W + (size_t)(k0 + k) * N + col0 + n4);
      Bs[n4 + 0][k] = (f16)wv.x;
      Bs[n4 + 1][k] = (f16)wv.y;
      Bs[n4 + 2][k] = (f16)wv.z;
      Bs[n4 + 3][k] = (f16)wv.w;
    }
    __syncthreads();
    f16x8 af[2], bfr[2];
#pragma unroll
    for (int tr = 0; tr < 2; ++tr)
      af[tr] = *(const f16x8*)&As[rw * 32 + tr * 16 + lr][quad * 8];
#pragma unroll
    for (int tc = 0; tc < 2; ++tc)
      bfr[tc] = *(const f16x8*)&Bs[cw * 32 + tc * 16 + lr][quad * 8];
#pragma unroll
    for (int tr = 0; tr < 2; ++tr)
#pragma unroll
      for (int tc = 0; tc < 2; ++tc)
        acc[tr][tc] = __builtin_amdgcn_mfma_f32_16x16x32_f16(af[tr], bfr[tc], acc[tr][tc], 0, 0, 0);
    __syncthreads();
  }
#pragma unroll
  for (int tc = 0; tc < 2; ++tc) {
    int col = col0 + cw * 32 + tc * 16 + lr;
    float bb = bias ? bias[col] : 0.0f;
#pragma unroll
    for (int tr = 0; tr < 2; ++tr) {
#pragma unroll
      for (int r = 0; r < 4; ++r) {
        int row = row0 + rw * 32 + tr * 16 + quad * 4 + r;
        if (row < M) {
          float x = acc[tr][tc][r] + bb;
          if (rowscale) x *= rowscale[row];
          if (SILU) x = silu_f(x);
          size_t o = (size_t)row * N + col;
          if (OUT == 0) ((float*)Cout)[o] = x;
          else          ((f16*)Cout)[o] = (f16)x;
        }
      }
    }
  }
}

// ---------------- dual-weight f16 MFMA GEMM: C1 = A@W1, C2 = A@W2 (fp32 A/out) ----------------
__global__ __launch_bounds__(256) void gemm_dual_kernel(
    const float* __restrict__ A, const float* __restrict__ W1,
    const float* __restrict__ W2, float* __restrict__ C1, float* __restrict__ C2,
    int M, int N, int K)
{
  __shared__ f16 As[64][40];
  __shared__ f16 Bs1[64][40];
  __shared__ f16 Bs2[64][40];
  int t = threadIdx.x;
  int wave = t >> 6, lane = t & 63;
  int rw = wave & 1, cw = wave >> 1;
  int lr = lane & 15, quad = lane >> 4;
  int row0 = blockIdx.x * 64, col0 = blockIdx.y * 64;
  floatx4 acc1[2][2] = {};
  floatx4 acc2[2][2] = {};
  for (int k0 = 0; k0 < K; k0 += 32) {
#pragma unroll
    for (int u0 = 0; u0 < 2; ++u0) {
      int u = t + u0 * 256;
      int m = u >> 3, c4 = (u & 7) * 4;
      float4 av = make_float4(0.f, 0.f, 0.f, 0.f);
      if (row0 + m < M) av = *(const float4*)(A + (size_t)(row0 + m) * K + k0 + c4);
      f16x4 hv;
      hv[0] = (f16)av.x; hv[1] = (f16)av.y; hv[2] = (f16)av.z; hv[3] = (f16)av.w;
      *(f16x4*)&As[m][c4] = hv;
    }
#pragma unroll
    for (int u0 = 0; u0 < 2; ++u0) {
      int u = t + u0 * 256;
      int k = u >> 4, n4 = (u & 15) * 4;
      float4 wv = *(const float4*)(W1 + (size_t)(k0 + k) * N + col0 + n4);
      Bs1[n4 + 0][k] = (f16)wv.x;
      Bs1[n4 + 1][k] = (f16)wv.y;
      Bs1[n4 + 2][k] = (f16)wv.z;
      Bs1[n4 + 3][k] = (f16)wv.w;
      float4 xv = *(const float4*)(W2 + (size_t)(k0 + k) * N + col0 + n4);
      Bs2[n4 + 0][k] = (f16)xv.x;
      Bs2[n4 + 1][k] = (f16)xv.y;
      Bs2[n4 + 2][k] = (f16)xv.z;
      Bs2[n4 + 3][k] = (f16)xv.w;
    }
    __syncthreads();
    f16x8 af[2], b1[2], b2[2];
#pragma unroll
    for (int tr = 0; tr < 2; ++tr)
      af[tr] = *(const f16x8*)&As[rw * 32 + tr * 16 + lr][quad * 8];
#pragma unroll
    for (int tc = 0; tc < 2; ++tc) {
      b1[tc] = *(const f16x8*)&Bs1[cw * 32 + tc * 16 + lr][quad * 8];
      b2[tc] = *(const f16x8*)&Bs2[cw * 32 + tc * 16 + lr][quad * 8];
    }
#pragma unroll
    for (int tr = 0; tr < 2; ++tr)
#pragma unroll
      for (int tc = 0; tc < 2; ++tc) {
        acc1[tr][tc] = __builtin_amdgcn_mfma_f32_16x16x32_f16(af[tr], b1[tc], acc1[tr][tc], 0, 0, 0);
        acc2[tr][tc] = __builtin_amdgcn_mfma_f32_16x16x32_f16(af[tr], b2[tc], acc2[tr][tc], 0, 0, 0);
      }
    __syncthreads();
  }
#pragma unroll
  for (int tc = 0; tc < 2; ++tc) {
    int col = col0 + cw * 32 + tc * 16 + lr;
#pragma unroll
    for (int tr = 0; tr < 2; ++tr) {
#pragma unroll
      for (int r = 0; r < 4; ++r) {
        int row = row0 + rw * 32 + tr * 16 + quad * 4 + r;
        if (row < M) {
          C1[(size_t)row * N + col] = acc1[tr][tc][r];
          C2[(size_t)row * N + col] = acc2[tr][tc][r];
        }
      }
    }
  }
}

// ---------------- gather message with FUSED w_s ----------------
// w_s = env*(rbf@dist_w + dist_b) computed inline: each thread preloads its
// 3 feature-columns of dist_w (+bias as row 20) into 63 registers, then per
// edge does 63 FMAs on the env-prefolded f16 rbf row. Kills the E*384 f16
// ws intermediate (123 MB write + 123 MB read per layer) and the ws_kernel.
__global__ __launch_bounds__(512, 4) void message_kernel(
    const int* __restrict__ nbrj_s, const float* __restrict__ unit_s,
    const f16* __restrict__ rbf_h, const float* __restrict__ dw,
    const float* __restrict__ db, const f16* __restrict__ phi_h,
    const f16* __restrict__ vh_in, const float* __restrict__ v_in,
    float* __restrict__ s, float* __restrict__ v_out,
    const int* __restrict__ start, int N)
{
  __shared__ float part[3][4][128];
  int i = blockIdx.x;
  int t = threadIdx.x;
  int f = t & 127, h = t >> 7;   // h in 0..3
  // per-feature dist_w columns; row NRBF is the bias (pairs with rbf slot 20 = env)
  float dwc[NRBF + 1][3];
#pragma unroll
  for (int k = 0; k < NRBF; ++k) {
    dwc[k][0] = dw[k * 384 + f];
    dwc[k][1] = dw[k * 384 + 128 + f];
    dwc[k][2] = dw[k * 384 + 256 + f];
  }
  dwc[NRBF][0] = db[f];
  dwc[NRBF][1] = db[128 + f];
  dwc[NRBF][2] = db[256 + f];
  int e0 = start[i], e1 = start[i + 1];
  int len = e1 - e0;
  int me0 = e0 + (len * h) / 4;
  int me1 = e0 + (len * (h + 1)) / 4;
  float acc_s = 0.f, av0 = 0.f, av1 = 0.f, av2 = 0.f;
  for (int e = me0; e < me1; ++e) {
    int j = nbrj_s[e];
    const f16* rp = rbf_h + (size_t)e * 32;
    f16x8 r0 = *(const f16x8*)rp;
    f16x8 r1 = *(const f16x8*)(rp + 8);
    f16x8 r2 = *(const f16x8*)(rp + 16);
    float rb[NRBF + 1];
#pragma unroll
    for (int q = 0; q < 8; ++q) rb[q] = (float)r0[q];
#pragma unroll
    for (int q = 0; q < 8; ++q) rb[8 + q] = (float)r1[q];
#pragma unroll
    for (int q = 0; q < 5; ++q) rb[16 + q] = (float)r2[q];
    float ws0 = 0.f, ws1 = 0.f, ws2 = 0.f;
#pragma unroll
    for (int k = 0; k <= NRBF; ++k) {
      ws0 = fmaf(rb[k], dwc[k][0], ws0);
      ws1 = fmaf(rb[k], dwc[k][1], ws1);
      ws2 = fmaf(rb[k], dwc[k][2], ws2);
    }
    const f16* ph = phi_h + (size_t)j * 384;
    float inv0 = (float)ph[f] * ws0;
    float inv1 = (float)ph[128 + f] * ws1;
    float inv2 = (float)ph[256 + f] * ws2;
    float ux = unit_s[3 * e + 0], uy = unit_s[3 * e + 1], uz = unit_s[3 * e + 2];
    const f16* vj = vh_in + (size_t)j * 384;
    acc_s += inv1;
    av0 = fmaf(inv0, (float)vj[f],       fmaf(inv2, ux, av0));
    av1 = fmaf(inv0, (float)vj[128 + f], fmaf(inv2, uy, av1));
    av2 = fmaf(inv0, (float)vj[256 + f], fmaf(inv2, uz, av2));
  }
  if (h >= 1) {
    part[h - 1][0][f] = acc_s;
    part[h - 1][1][f] = av0;
    part[h - 1][2][f] = av1;
    part[h - 1][3][f] = av2;
  }
  __syncthreads();
  if (h == 0) {
#pragma unroll
    for (int q = 0; q < 3; ++q) {   // fixed order: q1, q2, q3
      acc_s += part[q][0][f];
      av0   += part[q][1][f];
      av1   += part[q][2][f];
      av2   += part[q][3][f];
    }
    s[(size_t)i * 128 + f] += acc_s;
    size_t o = (size_t)i * 384 + f;
    v_out[o]       = v_in[o]       + av0;
    v_out[o + 128] = v_in[o + 128] + av1;
    v_out[o + 256] = v_in[o + 256] + av2;
  }
}

// ---------------- s_stack = [s, ||v_v||] (f16 out) ----------------
__global__ __launch_bounds__(256) void stack_kernel(
    const float* __restrict__ s, const float* __restrict__ v_v,
    f16* __restrict__ s_stack, int N)
{
  int idx = blockIdx.x * 256 + threadIdx.x;
  if (idx >= N * 128) return;
  int n = idx >> 7, g = idx & 127;
  float a = v_v[(size_t)n * 384 + g];
  float b = v_v[(size_t)n * 384 + 128 + g];
  float c = v_v[(size_t)n * 384 + 256 + g];
  s_stack[(size_t)n * 256 + g] = (f16)s[idx];
  s_stack[(size_t)n * 256 + 128 + g] = (f16)sqrtf(a * a + b * b + c * c + EPS_F);
}

// ---------------- gated update of s, v (+ f16 mirrors for next-layer reads) ----------------
__global__ __launch_bounds__(256) void apply_kernel(
    float* __restrict__ s, f16* __restrict__ s_h,
    float* __restrict__ v, f16* __restrict__ v_h,
    const float* __restrict__ u_v, const float* __restrict__ v_v,
    const float* __restrict__ sp, int N)
{
  int idx = blockIdx.x * 256 + threadIdx.x;
  if (idx >= N * 128) return;
  int n = idx >> 7, g = idx & 127;
  float sp0 = sp[(size_t)n * 384 + g];
  float sp1 = sp[(size_t)n * 384 + 128 + g];
  float sp2 = sp[(size_t)n * 384 + 256 + g];
  float dot = 0.f;
#pragma unroll
  for (int c = 0; c < 3; ++c) {
    size_t o = (size_t)n * 384 + c * 128 + g;
    float uv = u_v[o];
    float vn = fmaf(uv, sp0, v[o]);
    v[o] = vn;
    v_h[o] = (f16)vn;
    dot = fmaf(uv, v_v[o], dot);
  }
  float sn = s[idx] + dot * sp1 + sp2;
  s[idx] = sn;
  s_h[idx] = (f16)sn;
}

// ---------------- fused f16 MFMA readout (unsorted edges; register-prefetched gathers) ----------------
__global__ __launch_bounds__(256) void readout_gemm_kernel(
    const int* __restrict__ nbr, const float* __restrict__ xyz,
    const f16* __restrict__ s_h, const f16* __restrict__ w1t,
    const float* __restrict__ b1, const float* __restrict__ w2,
    const float* __restrict__ b2, float* __restrict__ out, int E)
{
  __shared__ f16 As[64][40];
  __shared__ f16 Bs[64][40];
  __shared__ float red[2][64];
  __shared__ int ijc[64][2];
  int t = threadIdx.x;
  int wave = t >> 6, lane = t & 63;
  int rw = wave & 1, cw = wave >> 1;
  int lr = lane & 15, quad = lane >> 4;
  int e0b = blockIdx.x * 64;
  if (t < 64) {
    int e = e0b + t;
    if (e < E) { ijc[t][0] = nbr[2 * e]; ijc[t][1] = nbr[2 * e + 1]; }
    else { ijc[t][0] = 0; ijc[t][1] = 0; }
  }
  __syncthreads();
  int m = t >> 2;             // one row (edge) per thread
  int c8 = (t & 3) * 8;       // 8 features within 32-k window
  int im = ijc[m][0], jm = ijc[m][1];
  bool okm = (e0b + m) < E;
  // prefetch all 8 row-segments (4 windows x i/j) - independent loads in flight
  f16x8 xa[4], ya[4];
  if (okm) {
#pragma unroll
    for (int w = 0; w < 4; ++w) {
      xa[w] = *(const f16x8*)(s_h + (size_t)im * 128 + w * 32 + c8);
      ya[w] = *(const f16x8*)(s_h + (size_t)jm * 128 + w * 32 + c8);
    }
  } else {
#pragma unroll
    for (int w = 0; w < 4; ++w)
      for (int q = 0; q < 8; ++q) { xa[w][q] = (f16)0.0f; ya[w][q] = (f16)0.0f; }
  }
  floatx4 acc[2][2] = {};
#pragma unroll
  for (int w = 0; w < 4; ++w) {
    *(f16x8*)&As[m][c8] = xa[w] + ya[w];
    {
      int sm = t >> 2, sk = (t & 3) * 8;
      *(f16x8*)&Bs[sm][sk] = *(const f16x8*)(w1t + (size_t)sm * 128 + w * 32 + sk);
    }
    __syncthreads();
    f16x8 af[2], bfr[2];
#pragma unroll
    for (int tr = 0; tr < 2; ++tr)
      af[tr] = *(const f16x8*)&As[rw * 32 + tr * 16 + lr][quad * 8];
#pragma unroll
    for (int tc = 0; tc < 2; ++tc)
      bfr[tc] = *(const f16x8*)&Bs[cw * 32 + tc * 16 + lr][quad * 8];
#pragma unroll
    for (int tr = 0; tr < 2; ++tr)
#pragma unroll
      for (int tc = 0; tc < 2; ++tc)
        acc[tr][tc] = __builtin_amdgcn_mfma_f32_16x16x32_f16(af[tr], bfr[tc], acc[tr][tc], 0, 0, 0);
    __syncthreads();
  }
  float b1v[2], w2v[2];
#pragma unroll
  for (int tc = 0; tc < 2; ++tc) {
    int col = cw * 32 + tc * 16 + lr;
    b1v[tc] = b1[col];
    w2v[tc] = w2[col];
  }
#pragma unroll
  for (int tr = 0; tr < 2; ++tr) {
#pragma unroll
    for (int r = 0; r < 4; ++r) {
      float p = 0.f;
#pragma unroll
      for (int tc = 0; tc < 2; ++tc)
        p += silu_f(acc[tr][tc][r] + b1v[tc]) * w2v[tc];
#pragma unroll
      for (int ofs = 1; ofs < 16; ofs <<= 1) p += __shfl_xor(p, ofs, 64);
      if (lr == 0) red[cw][rw * 32 + tr * 16 + quad * 4 + r] = p;
    }
  }
  __syncthreads();
  if (t < 64) {
    int e = e0b + t;
    if (e < E) {
      float fs = red[0][t] + red[1][t] + b2[0];
      int i = ijc[t][0], j = ijc[t][1];
      float dx = xyz[3 * i + 0] - xyz[3 * j + 0];
      float dy = xyz[3 * i + 1] - xyz[3 * j + 1];
      float dz = xyz[3 * i + 2] - xyz[3 * j + 2];
      float dis = sqrtf(dx * dx + dy * dy + dz * dz);  // no EPS here (matches ref)
      float sc = fs / dis;
      float fx = sc * dx, fy = sc * dy, fz = sc * dz;
      atomicAdd(out + (size_t)i * 3 + 0, fx);
      atomicAdd(out + (size_t)i * 3 + 1, fy);
      atomicAdd(out + (size_t)i * 3 + 2, fz);
      atomicAdd(out + (size_t)j * 3 + 0, -fx);
      atomicAdd(out + (size_t)j * 3 + 1, -fy);
      atomicAdd(out + (size_t)j * 3 + 2, -fz);
    }
  }
}

extern "C" void kernel_launch(void* const* d_in, const int* in_sizes, int n_in,
                              void* d_out, int out_size, void* d_ws, size_t ws_size,
                              hipStream_t stream) {
  const float* xyz    = (const float*)d_in[0];
  const int*   z      = (const int*)d_in[1];
  const int*   nbr    = (const int*)d_in[2];
  const float* embed  = (const float*)d_in[3];
  const float* msg_w1 = (const float*)d_in[4];
  const float* msg_b1 = (const float*)d_in[5];
  const float* msg_w2 = (const float*)d_in[6];
  const float* msg_b2 = (const float*)d_in[7];
  const float* dist_w = (const float*)d_in[8];
  const float* dist_b = (const float*)d_in[9];
  const float* upd_u  = (const float*)d_in[10];
  const float* upd_v  = (const float*)d_in[11];
  const float* upd_w1 = (const float*)d_in[12];
  const float* upd_b1 = (const float*)d_in[13];
  const float* upd_w2 = (const float*)d_in[14];
  const float* upd_b2 = (const float*)d_in[15];
  const float* ero_w1 = (const float*)d_in[16];
  const float* ero_b1 = (const float*)d_in[17];
  const float* ero_w2 = (const float*)d_in[18];
  const float* ero_b2 = (const float*)d_in[19];

  const int N = in_sizes[1];      // 10000
  const int E = in_sizes[2] / 2;  // 160000
  const int L = 3;

  char* ws = (char*)d_ws;
  size_t off = 0;
  auto alloc = [&](size_t bytes) -> void* {
    void* p = ws + off;
    off += (bytes + 255) & ~(size_t)255;
    return p;
  };
  float* unit_s = (float*)alloc((size_t)E * 3 * 4);
  f16*   rbf_h  = (f16*)alloc((size_t)E * 32 * 2);
  int*   nbrj_s = (int*)alloc((size_t)E * 4);
  int*   order  = (int*)alloc((size_t)E * 4);
  float* s      = (float*)alloc((size_t)N * 128 * 4);
  f16*   s_h    = (f16*)alloc((size_t)N * 128 * 2);
  float* vA     = (float*)alloc((size_t)N * 384 * 4);
  float* vB     = (float*)alloc((size_t)N * 384 * 4);
  f16*   vhA    = (f16*)alloc((size_t)N * 384 * 2);
  f16*   vhB    = (f16*)alloc((size_t)N * 384 * 2);
  f16*   phi_h  = (f16*)alloc((size_t)N * 384 * 2);
  f16*   w1t    = (f16*)alloc((size_t)64 * 128 * 2);
  int*   histx  = (int*)alloc((size_t)(N + 1) * 4);
  int*   startp = (int*)alloc((size_t)(N + 1) * 4);
  int*   cursor = (int*)alloc((size_t)N * 4);
  // update-phase buffers (no longer overlaid with ws chunk; ws is fused away)
  float* u_v    = (float*)alloc((size_t)N * 384 * 4);
  float* v_v    = (float*)alloc((size_t)N * 384 * 4);
  float* sp     = (float*)alloc((size_t)N * 384 * 4);
  f16*   sstk_h = (f16*)alloc((size_t)N * 256 * 2);
  f16*   h_h    = (f16*)alloc((size_t)N * 128 * 2);

  auto cdiv = [](int a, int b) { return (a + b - 1) / b; };

  // ---- setup: deterministic CSR ----
  hipMemsetAsync(vA, 0, (size_t)N * 384 * 4, stream);
  hipMemsetAsync(vhA, 0, (size_t)N * 384 * 2, stream);
  hipMemsetAsync(histx, 0, (size_t)(N + 1) * 4, stream);
  hist_kernel<<<cdiv(E, 256), 256, 0, stream>>>(nbr, histx, E);
  scan_kernel<<<1, 1024, 0, stream>>>(histx, startp, cursor, N);
  scatter_id_kernel<<<cdiv(E, 256), 256, 0, stream>>>(nbr, cursor, order, E);
  segsort_kernel<<<cdiv(N, 4), 256, 0, stream>>>(order, startp, N);
  geom_fill_kernel<<<cdiv(E, 256), 256, 0, stream>>>(
      order, nbr, xyz, nbrj_s, unit_s, rbf_h, E);
  embed_kernel<<<cdiv(N * 128, 256), 256, 0, stream>>>(z, embed, s, s_h, N);
  w1t_kernel<<<cdiv(64 * 128, 256), 256, 0, stream>>>(ero_w1, w1t);

  float* v_cur = vA;  float* v_nxt = vB;
  f16*   vh_cur = vhA; f16*  vh_nxt = vhB;
  for (int l = 0; l < L; ++l) {
    // phi = silu(s @ msg_w1 + b1) @ msg_w2 + b2  -> f16 (A read from f16 mirror)
    gemm_kernel<true, 1, true><<<dim3(cdiv(N, 64), 2), 256, 0, stream>>>(
        s_h, msg_w1 + (size_t)l * 128 * 128, msg_b1 + (size_t)l * 128, nullptr, h_h, N, 128, 128);
    gemm_kernel<false, 1, true><<<dim3(cdiv(N, 64), 6), 256, 0, stream>>>(
        h_h, msg_w2 + (size_t)l * 128 * 384, msg_b2 + (size_t)l * 384, nullptr, phi_h, N, 384, 128);
    // message with fused w_s (no ws intermediate, no chunking)
    message_kernel<<<N, 512, 0, stream>>>(
        nbrj_s, unit_s, rbf_h,
        dist_w + (size_t)l * NRBF * 384, dist_b + (size_t)l * 384,
        phi_h, vh_cur, v_cur, s, v_nxt, startp, N);
    float* v = v_nxt;
    // update block
    gemm_dual_kernel<<<dim3(cdiv(N * 3, 64), 2), 256, 0, stream>>>(
        v, upd_u + (size_t)l * 128 * 128, upd_v + (size_t)l * 128 * 128,
        u_v, v_v, N * 3, 128, 128);
    stack_kernel<<<cdiv(N * 128, 256), 256, 0, stream>>>(s, v_v, sstk_h, N);
    gemm_kernel<true, 1, true><<<dim3(cdiv(N, 64), 2), 256, 0, stream>>>(
        sstk_h, upd_w1 + (size_t)l * 256 * 128, upd_b1 + (size_t)l * 128, nullptr, h_h, N, 128, 256);
    gemm_kernel<false, 0, true><<<dim3(cdiv(N, 64), 6), 256, 0, stream>>>(
        h_h, upd_w2 + (size_t)l * 128 * 384, upd_b2 + (size_t)l * 384, nullptr, sp, N, 384, 128);
    apply_kernel<<<cdiv(N * 128, 256), 256, 0, stream>>>(
        s, s_h, v, vh_nxt, u_v, v_v, sp, N);
    v_cur = v_nxt;   v_nxt = (v_cur == vA) ? vB : vA;
    f16* th = vh_cur; vh_cur = vh_nxt; vh_nxt = th;
  }

  // fused f16 MFMA readout (unsorted edges, register-prefetched gathers)
  hipMemsetAsync(d_out, 0, (size_t)out_size * 4, stream);
  readout_gemm_kernel<<<cdiv(E, 64), 256, 0, stream>>>(
      nbr, xyz, s_h, w1t, ero_b1, ero_w2, ero_b2, (float*)d_out, E);
}

// Round 2
// 824.279 us; speedup vs baseline: 1.2391x; 1.2391x over previous
//
#include <hip/hip_runtime.h>
#include <math.h>

#define EPS_F 1e-15f
#define NRBF 20
#define CUTOFF_F 5.0f
#define PI_F 3.14159265358979323846f

typedef unsigned short u16;
typedef _Float16 f16;
typedef f16 f16x8 __attribute__((ext_vector_type(8)));
typedef f16 f16x4 __attribute__((ext_vector_type(4)));
typedef float floatx4 __attribute__((ext_vector_type(4)));

__device__ __forceinline__ float silu_f(float x) { return x / (1.0f + expf(-x)); }

// ---------------- counting sort: histogram + scan ----------------
__global__ __launch_bounds__(256) void hist_kernel(
    const int* __restrict__ nbr, int* __restrict__ hist, int E)
{
  int e = blockIdx.x * 256 + threadIdx.x;
  if (e >= E) return;
  atomicAdd(hist + nbr[2 * e], 1);
}

// single-block exclusive scan, wave-shfl based (few barriers)
__global__ __launch_bounds__(1024) void scan_kernel(
    const int* __restrict__ hist, int* __restrict__ start,
    int* __restrict__ cursor, int N)
{
  __shared__ int wsum[16];
  __shared__ int carry_s;
  int tid = threadIdx.x;
  int lane = tid & 63, wid = tid >> 6;
  if (tid == 0) carry_s = 0;
  __syncthreads();
  for (int base = 0; base < N; base += 1024) {
    int x = (base + tid < N) ? hist[base + tid] : 0;
    int v = x;
#pragma unroll
    for (int o = 1; o < 64; o <<= 1) {
      int t2 = __shfl_up(v, o, 64);
      if (lane >= o) v += t2;
    }
    if (lane == 63) wsum[wid] = v;
    __syncthreads();
    if (tid < 16) {
      int w = wsum[tid];
#pragma unroll
      for (int o = 1; o < 16; o <<= 1) {
        int t2 = __shfl_up(w, o, 64);
        if (tid >= o) w += t2;
      }
      wsum[tid] = w;
    }
    __syncthreads();
    int wbase = (wid == 0) ? 0 : wsum[wid - 1];
    int incl = v + wbase;
    int carry = carry_s;
    if (base + tid < N) {
      int ex = carry + incl - x;
      start[base + tid] = ex;
      cursor[base + tid] = ex;
    }
    __syncthreads();
    if (tid == 1023) carry_s = carry + incl;
    __syncthreads();
  }
  if (tid == 0) start[N] = carry_s;
}

// ---------------- scatter edge IDs ----------------
__global__ __launch_bounds__(256) void scatter_id_kernel(
    const int* __restrict__ nbr, int* __restrict__ cursor,
    int* __restrict__ order, int E)
{
  int e = blockIdx.x * 256 + threadIdx.x;
  if (e >= E) return;
  int pos = atomicAdd(cursor + nbr[2 * e], 1);
  order[pos] = e;
}

// ---------------- canonicalize: wave rank-sort of each atom's segment ----------------
__global__ __launch_bounds__(256) void segsort_kernel(
    int* __restrict__ order, const int* __restrict__ start, int N)
{
  int wi = blockIdx.x * 4 + (threadIdx.x >> 6);
  int lane = threadIdx.x & 63;
  if (wi >= N) return;
  int s0 = start[wi], s1 = start[wi + 1];
  int len = s1 - s0;
  if (len <= 1) return;
  if (len <= 64) {
    int id = (lane < len) ? order[s0 + lane] : 0x7FFFFFFF;
    int rank = 0;
#pragma unroll
    for (int k = 0; k < 64; ++k) {
      int other = __shfl(id, k, 64);
      rank += (other < id) ? 1 : 0;
    }
    if (lane < len) order[s0 + rank] = id;
  } else if (lane == 0) {
    for (int a = s0 + 1; a < s1; ++a) {
      int key = order[a];
      int b = a - 1;
      while (b >= s0 && order[b] > key) { order[b + 1] = order[b]; --b; }
      order[b + 1] = key;
    }
  }
}

// ---------------- geometry gather-fill (deterministic) ----------------
// rbf_h row layout (32 f16): slots 0..19 = sin(k_n d)/d * env   (env pre-folded)
//                            slot  20    = env
//                            slots 21..31 = 0
// So w_s col = dot(rbf_row[0..20], [dist_w; dist_b] col).
__global__ __launch_bounds__(256) void geom_fill_kernel(
    const int* __restrict__ order, const int* __restrict__ nbr,
    const float* __restrict__ xyz, int2* __restrict__ ij_s,
    float* __restrict__ unit_s, f16* __restrict__ rbf_h, int E)
{
  int p = blockIdx.x * 256 + threadIdx.x;
  if (p >= E) return;
  int e = order[p];
  int i = nbr[2 * e], j = nbr[2 * e + 1];
  float dx = xyz[3 * j + 0] - xyz[3 * i + 0];
  float dy = xyz[3 * j + 1] - xyz[3 * i + 1];
  float dz = xyz[3 * j + 2] - xyz[3 * i + 2];
  float d2 = dx * dx + dy * dy + dz * dz + 3.0f * EPS_F;  // ref adds EPS per comp
  float d = sqrtf(d2);
  float inv_d = 1.0f / d;
  ij_s[p] = make_int2(i, j);
  unit_s[3 * p + 0] = dx * inv_d;
  unit_s[3 * p + 1] = dy * inv_d;
  unit_s[3 * p + 2] = dz * inv_d;
  float x = d * (PI_F / CUTOFF_F);
  float s1, c1;
  __sincosf(x, &s1, &c1);
  float envv = (d < CUTOFF_F) ? 0.5f * (c1 + 1.0f) : 0.0f;
  f16 tmp[32];
  float two_c = 2.0f * c1;
  float env_inv_d = envv * inv_d;
  float sp = 0.0f, sn = s1;           // Chebyshev recurrence for sin(n*x)
  tmp[0] = (f16)(sn * env_inv_d);
#pragma unroll
  for (int n = 1; n < NRBF; ++n) {
    float nx = two_c * sn - sp;
    sp = sn; sn = nx;
    tmp[n] = (f16)(sn * env_inv_d);
  }
  tmp[NRBF] = (f16)envv;
#pragma unroll
  for (int n = NRBF + 1; n < 32; ++n) tmp[n] = (f16)0.0f;
#pragma unroll
  for (int g = 0; g < 4; ++g)
    *(f16x8*)(rbf_h + (size_t)p * 32 + g * 8) = *(f16x8*)&tmp[g * 8];
}

// ---------------- s = embed[z] (fp32 + f16 mirror) ----------------
__global__ __launch_bounds__(256) void embed_kernel(
    const int* __restrict__ z, const float* __restrict__ embed,
    float* __restrict__ s, f16* __restrict__ s_h, int N)
{
  int idx = blockIdx.x * 256 + threadIdx.x;
  if (idx >= N * 128) return;
  int n = idx >> 7, f = idx & 127;
  float x = embed[z[n] * 128 + f];
  s[idx] = x;
  s_h[idx] = (f16)x;
}

__global__ __launch_bounds__(256) void w1t_kernel(
    const float* __restrict__ w1, f16* __restrict__ w1t)
{
  int idx = blockIdx.x * 256 + threadIdx.x;
  if (idx >= 64 * 128) return;
  int n = idx >> 7, k = idx & 127;
  w1t[idx] = (f16)w1[(size_t)k * 64 + n];
}

// ---------------- f16 MFMA GEMM ----------------
template <bool SILU, int OUT, bool AH>
__global__ __launch_bounds__(256) void gemm_kernel(
    const void* __restrict__ Ap, const float* __restrict__ W,
    const float* __restrict__ bias, const float* __restrict__ rowscale,
    void* __restrict__ Cout, int M, int N, int K)
{
  __shared__ f16 As[64][40];
  __shared__ f16 Bs[64][40];
  int t = threadIdx.x;
  int wave = t >> 6, lane = t & 63;
  int rw = wave & 1, cw = wave >> 1;
  int lr = lane & 15, quad = lane >> 4;
  int row0 = blockIdx.x * 64, col0 = blockIdx.y * 64;
  floatx4 acc[2][2] = {};
  for (int k0 = 0; k0 < K; k0 += 32) {
    if (AH) {
      const f16* A = (const f16*)Ap;
      int sm = t >> 2, sk = (t & 3) * 8;
      f16x8 av;
      if (row0 + sm < M) av = *(const f16x8*)(A + (size_t)(row0 + sm) * K + k0 + sk);
      else { for (int q = 0; q < 8; ++q) av[q] = (f16)0.0f; }
      *(f16x8*)&As[sm][sk] = av;
    } else {
      const float* A = (const float*)Ap;
#pragma unroll
      for (int u0 = 0; u0 < 2; ++u0) {
        int u = t + u0 * 256;
        int m = u >> 3, c4 = (u & 7) * 4;
        float4 av = make_float4(0.f, 0.f, 0.f, 0.f);
        if (row0 + m < M) av = *(const float4*)(A + (size_t)(row0 + m) * K + k0 + c4);
        f16x4 hv;
        hv[0] = (f16)av.x; hv[1] = (f16)av.y; hv[2] = (f16)av.z; hv[3] = (f16)av.w;
        *(f16x4*)&As[m][c4] = hv;
      }
    }
#pragma unroll
    for (int u0 = 0; u0 < 2; ++u0) {
      int u = t + u0 * 256;
      int k = u >> 4, n4 = (u & 15) * 4;
      float4 wv = *(const float4*)(W + (size_t)(k0 + k) * N + col0 + n4);
      Bs[n4 + 0][k] = (f16)wv.x;
      Bs[n4 + 1][k] = (f16)wv.y;
      Bs[n4 + 2][k] = (f16)wv.z;
      Bs[n4 + 3][k] = (f16)wv.w;
    }
    __syncthreads();
    f16x8 af[2], bfr[2];
#pragma unroll
    for (int tr = 0; tr < 2; ++tr)
      af[tr] = *(const f16x8*)&As[rw * 32 + tr * 16 + lr][quad * 8];
#pragma unroll
    for (int tc = 0; tc < 2; ++tc)
      bfr[tc] = *(const f16x8*)&Bs[cw * 32 + tc * 16 + lr][quad * 8];
#pragma unroll
    for (int tr = 0; tr < 2; ++tr)
#pragma unroll
      for (int tc = 0; tc < 2; ++tc)
        acc[tr][tc] = __builtin_amdgcn_mfma_f32_16x16x32_f16(af[tr], bfr[tc], acc[tr][tc], 0, 0, 0);
    __syncthreads();
  }
#pragma unroll
  for (int tc = 0; tc < 2; ++tc) {
    int col = col0 + cw * 32 + tc * 16 + lr;
    float bb = bias ? bias[col] : 0.0f;
#pragma unroll
    for (int tr = 0; tr < 2; ++tr) {
#pragma unroll
      for (int r = 0; r < 4; ++r) {
        int row = row0 + rw * 32 + tr * 16 + quad * 4 + r;
        if (row < M) {
          float x = acc[tr][tc][r] + bb;
          if (rowscale) x *= rowscale[row];
          if (SILU) x = silu_f(x);
          size_t o = (size_t)row * N + col;
          if (OUT == 0) ((float*)Cout)[o] = x;
          else          ((f16*)Cout)[o] = (f16)x;
        }
      }
    }
  }
}

// ---------------- dual-weight f16 MFMA GEMM: C1 = A@W1, C2 = A@W2 (fp32 A/out) ----------------
__global__ __launch_bounds__(256) void gemm_dual_kernel(
    const float* __restrict__ A, const float* __restrict__ W1,
    const float* __restrict__ W2, float* __restrict__ C1, float* __restrict__ C2,
    int M, int N, int K)
{
  __shared__ f16 As[64][40];
  __shared__ f16 Bs1[64][40];
  __shared__ f16 Bs2[64][40];
  int t = threadIdx.x;
  int wave = t >> 6, lane = t & 63;
  int rw = wave & 1, cw = wave >> 1;
  int lr = lane & 15, quad = lane >> 4;
  int row0 = blockIdx.x * 64, col0 = blockIdx.y * 64;
  floatx4 acc1[2][2] = {};
  floatx4 acc2[2][2] = {};
  for (int k0 = 0; k0 < K; k0 += 32) {
#pragma unroll
    for (int u0 = 0; u0 < 2; ++u0) {
      int u = t + u0 * 256;
      int m = u >> 3, c4 = (u & 7) * 4;
      float4 av = make_float4(0.f, 0.f, 0.f, 0.f);
      if (row0 + m < M) av = *(const float4*)(A + (size_t)(row0 + m) * K + k0 + c4);
      f16x4 hv;
      hv[0] = (f16)av.x; hv[1] = (f16)av.y; hv[2] = (f16)av.z; hv[3] = (f16)av.w;
      *(f16x4*)&As[m][c4] = hv;
    }
#pragma unroll
    for (int u0 = 0; u0 < 2; ++u0) {
      int u = t + u0 * 256;
      int k = u >> 4, n4 = (u & 15) * 4;
      float4 wv = *(const float4*)(W1 + (size_t)(k0 + k) * N + col0 + n4);
      Bs1[n4 + 0][k] = (f16)wv.x;
      Bs1[n4 + 1][k] = (f16)wv.y;
      Bs1[n4 + 2][k] = (f16)wv.z;
      Bs1[n4 + 3][k] = (f16)wv.w;
      float4 xv = *(const float4*)(W2 + (size_t)(k0 + k) * N + col0 + n4);
      Bs2[n4 + 0][k] = (f16)xv.x;
      Bs2[n4 + 1][k] = (f16)xv.y;
      Bs2[n4 + 2][k] = (f16)xv.z;
      Bs2[n4 + 3][k] = (f16)xv.w;
    }
    __syncthreads();
    f16x8 af[2], b1[2], b2[2];
#pragma unroll
    for (int tr = 0; tr < 2; ++tr)
      af[tr] = *(const f16x8*)&As[rw * 32 + tr * 16 + lr][quad * 8];
#pragma unroll
    for (int tc = 0; tc < 2; ++tc) {
      b1[tc] = *(const f16x8*)&Bs1[cw * 32 + tc * 16 + lr][quad * 8];
      b2[tc] = *(const f16x8*)&Bs2[cw * 32 + tc * 16 + lr][quad * 8];
    }
#pragma unroll
    for (int tr = 0; tr < 2; ++tr)
#pragma unroll
      for (int tc = 0; tc < 2; ++tc) {
        acc1[tr][tc] = __builtin_amdgcn_mfma_f32_16x16x32_f16(af[tr], b1[tc], acc1[tr][tc], 0, 0, 0);
        acc2[tr][tc] = __builtin_amdgcn_mfma_f32_16x16x32_f16(af[tr], b2[tc], acc2[tr][tc], 0, 0, 0);
      }
    __syncthreads();
  }
#pragma unroll
  for (int tc = 0; tc < 2; ++tc) {
    int col = col0 + cw * 32 + tc * 16 + lr;
#pragma unroll
    for (int tr = 0; tr < 2; ++tr) {
#pragma unroll
      for (int r = 0; r < 4; ++r) {
        int row = row0 + rw * 32 + tr * 16 + quad * 4 + r;
        if (row < M) {
          C1[(size_t)row * N + col] = acc1[tr][tc][r];
          C2[(size_t)row * N + col] = acc2[tr][tc][r];
        }
      }
    }
  }
}

// ---------------- edge-block gather message with fused w_s ----------------
// Block = 384 threads = (g in 0..2) x (f in 0..127); each thread owns ONE of
// the 384 w_s columns -> dwc[21] fits in registers (round-1's 63-reg version
// spilled to scratch, VGPR=48 + scratch loads = 192us).
// Block processes MSG_EPB contiguous SORTED edges; per-thread partials flush
// on atom-boundary (block-uniform) via atomicAdd into s / v (in-place).
// Software pipeline: ij prefetched 2 ahead; rbf/phi/vj/unit 1 ahead.
#define MSG_EPB 64
__global__ __launch_bounds__(384, 4) void message_kernel(
    const int2* __restrict__ ij_s, const float* __restrict__ unit_s,
    const f16* __restrict__ rbf_h, const float* __restrict__ dw,
    const float* __restrict__ db, const f16* __restrict__ phi_h,
    const f16* __restrict__ vh, float* __restrict__ s,
    float* __restrict__ v, int E)
{
  int t = threadIdx.x;
  int f = t & 127, g = t >> 7;        // g in 0..2
  int col = (g << 7) + f;
  // per-thread column of [dist_w ; dist_b] : 21 f32 regs
  float dwc[NRBF + 1];
#pragma unroll
  for (int k = 0; k < NRBF; ++k) dwc[k] = dw[k * 384 + col];
  dwc[NRBF] = db[col];

  int e_lo = blockIdx.x * MSG_EPB;
  if (e_lo >= E) return;
  int e_hi = e_lo + MSG_EPB; if (e_hi > E) e_hi = E;

  float a0 = 0.f, a1 = 0.f, a2 = 0.f;
  int prev_i = -1;

  // ---- prologue: ij for e_lo and e_lo+1; data for e_lo ----
  int2 ij_c = ij_s[e_lo];
  int ep1 = (e_lo + 1 < e_hi) ? e_lo + 1 : e_lo;
  int2 ij_n = ij_s[ep1];
  const f16* rpc = rbf_h + (size_t)e_lo * 32;
  f16x8 r0c = *(const f16x8*)rpc;
  f16x8 r1c = *(const f16x8*)(rpc + 8);
  f16x8 r2c = *(const f16x8*)(rpc + 16);
  f16 ph_c = phi_h[(size_t)ij_c.y * 384 + col];
  f16 vj0c = (f16)0.f, vj1c = (f16)0.f, vj2c = (f16)0.f;
  float u0c = 0.f, u1c = 0.f, u2c = 0.f;
  if (g == 0) {
    const f16* vjp = vh + (size_t)ij_c.y * 384 + f;
    vj0c = vjp[0]; vj1c = vjp[128]; vj2c = vjp[256];
  } else if (g == 2) {
    u0c = unit_s[3 * e_lo + 0]; u1c = unit_s[3 * e_lo + 1]; u2c = unit_s[3 * e_lo + 2];
  }

  for (int e = e_lo; e < e_hi; ++e) {
    // ---- prefetch stage: ij two ahead, edge-data one ahead ----
    int ep2 = (e + 2 < e_hi) ? e + 2 : e;
    int2 ij_nn = ij_s[ep2];
    int ep = (e + 1 < e_hi) ? e + 1 : e;
    const f16* rpn = rbf_h + (size_t)ep * 32;
    f16x8 r0n = *(const f16x8*)rpn;
    f16x8 r1n = *(const f16x8*)(rpn + 8);
    f16x8 r2n = *(const f16x8*)(rpn + 16);
    f16 ph_n = phi_h[(size_t)ij_n.y * 384 + col];
    f16 vj0n = (f16)0.f, vj1n = (f16)0.f, vj2n = (f16)0.f;
    float u0n = 0.f, u1n = 0.f, u2n = 0.f;
    if (g == 0) {
      const f16* vjp = vh + (size_t)ij_n.y * 384 + f;
      vj0n = vjp[0]; vj1n = vjp[128]; vj2n = vjp[256];
    } else if (g == 2) {
      u0n = unit_s[3 * ep + 0]; u1n = unit_s[3 * ep + 1]; u2n = unit_s[3 * ep + 2];
    }
    // ---- flush on atom change (block-uniform branch) ----
    if (ij_c.x != prev_i) {
      if (prev_i >= 0) {
        if (g == 1) {
          atomicAdd(s + (size_t)prev_i * 128 + f, a0);
        } else {
          float* vb = v + (size_t)prev_i * 384 + f;
          atomicAdd(vb, a0);
          atomicAdd(vb + 128, a1);
          atomicAdd(vb + 256, a2);
        }
        a0 = a1 = a2 = 0.f;
      }
      prev_i = ij_c.x;
    }
    // ---- compute current edge: ws = dot(rbf_row, dwc) (fma_mix) ----
    float wsA = 0.f, wsB = 0.f, wsC = 0.f;
#pragma unroll
    for (int q = 0; q < 8; ++q) wsA = fmaf((float)r0c[q], dwc[q], wsA);
#pragma unroll
    for (int q = 0; q < 8; ++q) wsB = fmaf((float)r1c[q], dwc[8 + q], wsB);
#pragma unroll
    for (int q = 0; q < 5; ++q) wsC = fmaf((float)r2c[q], dwc[16 + q], wsC);
    float ws = (wsA + wsB) + wsC;
    float inv = (float)ph_c * ws;
    if (g == 0) {
      a0 = fmaf(inv, (float)vj0c, a0);
      a1 = fmaf(inv, (float)vj1c, a1);
      a2 = fmaf(inv, (float)vj2c, a2);
    } else if (g == 1) {
      a0 += inv;
    } else {
      a0 = fmaf(inv, u0c, a0);
      a1 = fmaf(inv, u1c, a1);
      a2 = fmaf(inv, u2c, a2);
    }
    // ---- shift pipeline ----
    ij_c = ij_n; ij_n = ij_nn;
    r0c = r0n; r1c = r1n; r2c = r2n;
    ph_c = ph_n;
    vj0c = vj0n; vj1c = vj1n; vj2c = vj2n;
    u0c = u0n; u1c = u1n; u2c = u2n;
  }
  // ---- final flush ----
  if (prev_i >= 0) {
    if (g == 1) {
      atomicAdd(s + (size_t)prev_i * 128 + f, a0);
    } else {
      float* vb = v + (size_t)prev_i * 384 + f;
      atomicAdd(vb, a0);
      atomicAdd(vb + 128, a1);
      atomicAdd(vb + 256, a2);
    }
  }
}

// ---------------- s_stack = [s, ||v_v||] (f16 out) ----------------
__global__ __launch_bounds__(256) void stack_kernel(
    const float* __restrict__ s, const float* __restrict__ v_v,
    f16* __restrict__ s_stack, int N)
{
  int idx = blockIdx.x * 256 + threadIdx.x;
  if (idx >= N * 128) return;
  int n = idx >> 7, g = idx & 127;
  float a = v_v[(size_t)n * 384 + g];
  float b = v_v[(size_t)n * 384 + 128 + g];
  float c = v_v[(size_t)n * 384 + 256 + g];
  s_stack[(size_t)n * 256 + g] = (f16)s[idx];
  s_stack[(size_t)n * 256 + 128 + g] = (f16)sqrtf(a * a + b * b + c * c + EPS_F);
}

// ---------------- gated update of s, v (+ f16 mirrors for next-layer reads) ----------------
__global__ __launch_bounds__(256) void apply_kernel(
    float* __restrict__ s, f16* __restrict__ s_h,
    float* __restrict__ v, f16* __restrict__ v_h,
    const float* __restrict__ u_v, const float* __restrict__ v_v,
    const float* __restrict__ sp, int N)
{
  int idx = blockIdx.x * 256 + threadIdx.x;
  if (idx >= N * 128) return;
  int n = idx >> 7, g = idx & 127;
  float sp0 = sp[(size_t)n * 384 + g];
  float sp1 = sp[(size_t)n * 384 + 128 + g];
  float sp2 = sp[(size_t)n * 384 + 256 + g];
  float dot = 0.f;
#pragma unroll
  for (int c = 0; c < 3; ++c) {
    size_t o = (size_t)n * 384 + c * 128 + g;
    float uv = u_v[o];
    float vn = fmaf(uv, sp0, v[o]);
    v[o] = vn;
    v_h[o] = (f16)vn;
    dot = fmaf(uv, v_v[o], dot);
  }
  float sn = s[idx] + dot * sp1 + sp2;
  s[idx] = sn;
  s_h[idx] = (f16)sn;
}

// ---------------- fused f16 MFMA readout (unsorted edges; register-prefetched gathers) ----------------
__global__ __launch_bounds__(256) void readout_gemm_kernel(
    const int* __restrict__ nbr, const float* __restrict__ xyz,
    const f16* __restrict__ s_h, const f16* __restrict__ w1t,
    const float* __restrict__ b1, const float* __restrict__ w2,
    const float* __restrict__ b2, float* __restrict__ out, int E)
{
  __shared__ f16 As[64][40];
  __shared__ f16 Bs[64][40];
  __shared__ float red[2][64];
  __shared__ int ijc[64][2];
  int t = threadIdx.x;
  int wave = t >> 6, lane = t & 63;
  int rw = wave & 1, cw = wave >> 1;
  int lr = lane & 15, quad = lane >> 4;
  int e0b = blockIdx.x * 64;
  if (t < 64) {
    int e = e0b + t;
    if (e < E) { ijc[t][0] = nbr[2 * e]; ijc[t][1] = nbr[2 * e + 1]; }
    else { ijc[t][0] = 0; ijc[t][1] = 0; }
  }
  __syncthreads();
  int m = t >> 2;             // one row (edge) per thread
  int c8 = (t & 3) * 8;       // 8 features within 32-k window
  int im = ijc[m][0], jm = ijc[m][1];
  bool okm = (e0b + m) < E;
  // prefetch all 8 row-segments (4 windows x i/j) - independent loads in flight
  f16x8 xa[4], ya[4];
  if (okm) {
#pragma unroll
    for (int w = 0; w < 4; ++w) {
      xa[w] = *(const f16x8*)(s_h + (size_t)im * 128 + w * 32 + c8);
      ya[w] = *(const f16x8*)(s_h + (size_t)jm * 128 + w * 32 + c8);
    }
  } else {
#pragma unroll
    for (int w = 0; w < 4; ++w)
      for (int q = 0; q < 8; ++q) { xa[w][q] = (f16)0.0f; ya[w][q] = (f16)0.0f; }
  }
  floatx4 acc[2][2] = {};
#pragma unroll
  for (int w = 0; w < 4; ++w) {
    *(f16x8*)&As[m][c8] = xa[w] + ya[w];
    {
      int sm = t >> 2, sk = (t & 3) * 8;
      *(f16x8*)&Bs[sm][sk] = *(const f16x8*)(w1t + (size_t)sm * 128 + w * 32 + sk);
    }
    __syncthreads();
    f16x8 af[2], bfr[2];
#pragma unroll
    for (int tr = 0; tr < 2; ++tr)
      af[tr] = *(const f16x8*)&As[rw * 32 + tr * 16 + lr][quad * 8];
#pragma unroll
    for (int tc = 0; tc < 2; ++tc)
      bfr[tc] = *(const f16x8*)&Bs[cw * 32 + tc * 16 + lr][quad * 8];
#pragma unroll
    for (int tr = 0; tr < 2; ++tr)
#pragma unroll
      for (int tc = 0; tc < 2; ++tc)
        acc[tr][tc] = __builtin_amdgcn_mfma_f32_16x16x32_f16(af[tr], bfr[tc], acc[tr][tc], 0, 0, 0);
    __syncthreads();
  }
  float b1v[2], w2v[2];
#pragma unroll
  for (int tc = 0; tc < 2; ++tc) {
    int col = cw * 32 + tc * 16 + lr;
    b1v[tc] = b1[col];
    w2v[tc] = w2[col];
  }
#pragma unroll
  for (int tr = 0; tr < 2; ++tr) {
#pragma unroll
    for (int r = 0; r < 4; ++r) {
      float p = 0.f;
#pragma unroll
      for (int tc = 0; tc < 2; ++tc)
        p += silu_f(acc[tr][tc][r] + b1v[tc]) * w2v[tc];
#pragma unroll
      for (int ofs = 1; ofs < 16; ofs <<= 1) p += __shfl_xor(p, ofs, 64);
      if (lr == 0) red[cw][rw * 32 + tr * 16 + quad * 4 + r] = p;
    }
  }
  __syncthreads();
  if (t < 64) {
    int e = e0b + t;
    if (e < E) {
      float fs = red[0][t] + red[1][t] + b2[0];
      int i = ijc[t][0], j = ijc[t][1];
      float dx = xyz[3 * i + 0] - xyz[3 * j + 0];
      float dy = xyz[3 * i + 1] - xyz[3 * j + 1];
      float dz = xyz[3 * i + 2] - xyz[3 * j + 2];
      float dis = sqrtf(dx * dx + dy * dy + dz * dz);  // no EPS here (matches ref)
      float sc = fs / dis;
      float fx = sc * dx, fy = sc * dy, fz = sc * dz;
      atomicAdd(out + (size_t)i * 3 + 0, fx);
      atomicAdd(out + (size_t)i * 3 + 1, fy);
      atomicAdd(out + (size_t)i * 3 + 2, fz);
      atomicAdd(out + (size_t)j * 3 + 0, -fx);
      atomicAdd(out + (size_t)j * 3 + 1, -fy);
      atomicAdd(out + (size_t)j * 3 + 2, -fz);
    }
  }
}

extern "C" void kernel_launch(void* const* d_in, const int* in_sizes, int n_in,
                              void* d_out, int out_size, void* d_ws, size_t ws_size,
                              hipStream_t stream) {
  const float* xyz    = (const float*)d_in[0];
  const int*   z      = (const int*)d_in[1];
  const int*   nbr    = (const int*)d_in[2];
  const float* embed  = (const float*)d_in[3];
  const float* msg_w1 = (const float*)d_in[4];
  const float* msg_b1 = (const float*)d_in[5];
  const float* msg_w2 = (const float*)d_in[6];
  const float* msg_b2 = (const float*)d_in[7];
  const float* dist_w = (const float*)d_in[8];
  const float* dist_b = (const float*)d_in[9];
  const float* upd_u  = (const float*)d_in[10];
  const float* upd_v  = (const float*)d_in[11];
  const float* upd_w1 = (const float*)d_in[12];
  const float* upd_b1 = (const float*)d_in[13];
  const float* upd_w2 = (const float*)d_in[14];
  const float* upd_b2 = (const float*)d_in[15];
  const float* ero_w1 = (const float*)d_in[16];
  const float* ero_b1 = (const float*)d_in[17];
  const float* ero_w2 = (const float*)d_in[18];
  const float* ero_b2 = (const float*)d_in[19];

  const int N = in_sizes[1];      // 10000
  const int E = in_sizes[2] / 2;  // 160000
  const int L = 3;

  char* ws = (char*)d_ws;
  size_t off = 0;
  auto alloc = [&](size_t bytes) -> void* {
    void* p = ws + off;
    off += (bytes + 255) & ~(size_t)255;
    return p;
  };
  float* unit_s = (float*)alloc((size_t)E * 3 * 4);
  f16*   rbf_h  = (f16*)alloc((size_t)E * 32 * 2);
  int2*  ij_s   = (int2*)alloc((size_t)E * 8);
  int*   order  = (int*)alloc((size_t)E * 4);
  float* s      = (float*)alloc((size_t)N * 128 * 4);
  f16*   s_h    = (f16*)alloc((size_t)N * 128 * 2);
  float* vA     = (float*)alloc((size_t)N * 384 * 4);
  f16*   vhA    = (f16*)alloc((size_t)N * 384 * 2);
  f16*   phi_h  = (f16*)alloc((size_t)N * 384 * 2);
  f16*   w1t    = (f16*)alloc((size_t)64 * 128 * 2);
  int*   histx  = (int*)alloc((size_t)(N + 1) * 4);
  int*   startp = (int*)alloc((size_t)(N + 1) * 4);
  int*   cursor = (int*)alloc((size_t)N * 4);
  float* u_v    = (float*)alloc((size_t)N * 384 * 4);
  float* v_v    = (float*)alloc((size_t)N * 384 * 4);
  float* sp     = (float*)alloc((size_t)N * 384 * 4);
  f16*   sstk_h = (f16*)alloc((size_t)N * 256 * 2);
  f16*   h_h    = (f16*)alloc((size_t)N * 128 * 2);

  auto cdiv = [](int a, int b) { return (a + b - 1) / b; };

  // ---- setup: deterministic CSR ----
  hipMemsetAsync(vA, 0, (size_t)N * 384 * 4, stream);
  hipMemsetAsync(vhA, 0, (size_t)N * 384 * 2, stream);
  hipMemsetAsync(histx, 0, (size_t)(N + 1) * 4, stream);
  hist_kernel<<<cdiv(E, 256), 256, 0, stream>>>(nbr, histx, E);
  scan_kernel<<<1, 1024, 0, stream>>>(histx, startp, cursor, N);
  scatter_id_kernel<<<cdiv(E, 256), 256, 0, stream>>>(nbr, cursor, order, E);
  segsort_kernel<<<cdiv(N, 4), 256, 0, stream>>>(order, startp, N);
  geom_fill_kernel<<<cdiv(E, 256), 256, 0, stream>>>(
      order, nbr, xyz, ij_s, unit_s, rbf_h, E);
  embed_kernel<<<cdiv(N * 128, 256), 256, 0, stream>>>(z, embed, s, s_h, N);
  w1t_kernel<<<cdiv(64 * 128, 256), 256, 0, stream>>>(ero_w1, w1t);

  for (int l = 0; l < L; ++l) {
    // phi = silu(s @ msg_w1 + b1) @ msg_w2 + b2  -> f16 (A read from f16 mirror)
    gemm_kernel<true, 1, true><<<dim3(cdiv(N, 64), 2), 256, 0, stream>>>(
        s_h, msg_w1 + (size_t)l * 128 * 128, msg_b1 + (size_t)l * 128, nullptr, h_h, N, 128, 128);
    gemm_kernel<false, 1, true><<<dim3(cdiv(N, 64), 6), 256, 0, stream>>>(
        h_h, msg_w2 + (size_t)l * 128 * 384, msg_b2 + (size_t)l * 384, nullptr, phi_h, N, 384, 128);
    // edge-block message with fused w_s; atomic flush into s / v (in place)
    message_kernel<<<cdiv(E, MSG_EPB), 384, 0, stream>>>(
        ij_s, unit_s, rbf_h,
        dist_w + (size_t)l * NRBF * 384, dist_b + (size_t)l * 384,
        phi_h, vhA, s, vA, E);
    // update block
    gemm_dual_kernel<<<dim3(cdiv(N * 3, 64), 2), 256, 0, stream>>>(
        vA, upd_u + (size_t)l * 128 * 128, upd_v + (size_t)l * 128 * 128,
        u_v, v_v, N * 3, 128, 128);
    stack_kernel<<<cdiv(N * 128, 256), 256, 0, stream>>>(s, v_v, sstk_h, N);
    gemm_kernel<true, 1, true><<<dim3(cdiv(N, 64), 2), 256, 0, stream>>>(
        sstk_h, upd_w1 + (size_t)l * 256 * 128, upd_b1 + (size_t)l * 128, nullptr, h_h, N, 128, 256);
    gemm_kernel<false, 0, true><<<dim3(cdiv(N, 64), 6), 256, 0, stream>>>(
        h_h, upd_w2 + (size_t)l * 128 * 384, upd_b2 + (size_t)l * 384, nullptr, sp, N, 384, 128);
    apply_kernel<<<cdiv(N * 128, 256), 256, 0, stream>>>(
        s, s_h, vA, vhA, u_v, v_v, sp, N);
  }

  // fused f16 MFMA readout (unsorted edges, register-prefetched gathers)
  hipMemsetAsync(d_out, 0, (size_t)out_size * 4, stream);
  readout_gemm_kernel<<<cdiv(E, 64), 256, 0, stream>>>(
      nbr, xyz, s_h, w1t, ero_b1, ero_w2, ero_b2, (float*)d_out, E);
}

// Round 3
// 768.698 us; speedup vs baseline: 1.3287x; 1.0723x over previous
//
#include <hip/hip_runtime.h>
#include <math.h>

#define EPS_F 1e-15f
#define NRBF 20
#define CUTOFF_F 5.0f
#define PI_F 3.14159265358979323846f

typedef unsigned short u16;
typedef _Float16 f16;
typedef f16 f16x8 __attribute__((ext_vector_type(8)));
typedef f16 f16x4 __attribute__((ext_vector_type(4)));
typedef f16 f16x2 __attribute__((ext_vector_type(2)));
typedef float floatx4 __attribute__((ext_vector_type(4)));

__device__ __forceinline__ float silu_f(float x) { return x / (1.0f + expf(-x)); }

// ---------------- counting sort: histogram + scan ----------------
__global__ __launch_bounds__(256) void hist_kernel(
    const int* __restrict__ nbr, int* __restrict__ hist, int E)
{
  int e = blockIdx.x * 256 + threadIdx.x;
  if (e >= E) return;
  atomicAdd(hist + nbr[2 * e], 1);
}

// single-block exclusive scan, wave-shfl based (few barriers)
__global__ __launch_bounds__(1024) void scan_kernel(
    const int* __restrict__ hist, int* __restrict__ start,
    int* __restrict__ cursor, int N)
{
  __shared__ int wsum[16];
  __shared__ int carry_s;
  int tid = threadIdx.x;
  int lane = tid & 63, wid = tid >> 6;
  if (tid == 0) carry_s = 0;
  __syncthreads();
  for (int base = 0; base < N; base += 1024) {
    int x = (base + tid < N) ? hist[base + tid] : 0;
    int v = x;
#pragma unroll
    for (int o = 1; o < 64; o <<= 1) {
      int t2 = __shfl_up(v, o, 64);
      if (lane >= o) v += t2;
    }
    if (lane == 63) wsum[wid] = v;
    __syncthreads();
    if (tid < 16) {
      int w = wsum[tid];
#pragma unroll
      for (int o = 1; o < 16; o <<= 1) {
        int t2 = __shfl_up(w, o, 64);
        if (tid >= o) w += t2;
      }
      wsum[tid] = w;
    }
    __syncthreads();
    int wbase = (wid == 0) ? 0 : wsum[wid - 1];
    int incl = v + wbase;
    int carry = carry_s;
    if (base + tid < N) {
      int ex = carry + incl - x;
      start[base + tid] = ex;
      cursor[base + tid] = ex;
    }
    __syncthreads();
    if (tid == 1023) carry_s = carry + incl;
    __syncthreads();
  }
  if (tid == 0) start[N] = carry_s;
}

// ---------------- scatter edge IDs ----------------
__global__ __launch_bounds__(256) void scatter_id_kernel(
    const int* __restrict__ nbr, int* __restrict__ cursor,
    int* __restrict__ order, int E)
{
  int e = blockIdx.x * 256 + threadIdx.x;
  if (e >= E) return;
  int pos = atomicAdd(cursor + nbr[2 * e], 1);
  order[pos] = e;
}

// ---------------- canonicalize: wave rank-sort of each atom's segment ----------------
__global__ __launch_bounds__(256) void segsort_kernel(
    int* __restrict__ order, const int* __restrict__ start, int N)
{
  int wi = blockIdx.x * 4 + (threadIdx.x >> 6);
  int lane = threadIdx.x & 63;
  if (wi >= N) return;
  int s0 = start[wi], s1 = start[wi + 1];
  int len = s1 - s0;
  if (len <= 1) return;
  if (len <= 64) {
    int id = (lane < len) ? order[s0 + lane] : 0x7FFFFFFF;
    int rank = 0;
#pragma unroll
    for (int k = 0; k < 64; ++k) {
      int other = __shfl(id, k, 64);
      rank += (other < id) ? 1 : 0;
    }
    if (lane < len) order[s0 + rank] = id;
  } else if (lane == 0) {
    for (int a = s0 + 1; a < s1; ++a) {
      int key = order[a];
      int b = a - 1;
      while (b >= s0 && order[b] > key) { order[b + 1] = order[b]; --b; }
      order[b + 1] = key;
    }
  }
}

// ---------------- geometry gather-fill (deterministic) ----------------
// rbf_h row layout (32 f16): slots 0..19 = sin(k_n d)/d * env   (env pre-folded)
//                            slot  20    = env
//                            slots 21..31 = 0
// So w_s col = dot(rbf_row[0..20], [dist_w; dist_b] col).
__global__ __launch_bounds__(256) void geom_fill_kernel(
    const int* __restrict__ order, const int* __restrict__ nbr,
    const float* __restrict__ xyz, int2* __restrict__ ij_s,
    float* __restrict__ unit_s, f16* __restrict__ rbf_h, int E)
{
  int p = blockIdx.x * 256 + threadIdx.x;
  if (p >= E) return;
  int e = order[p];
  int i = nbr[2 * e], j = nbr[2 * e + 1];
  float dx = xyz[3 * j + 0] - xyz[3 * i + 0];
  float dy = xyz[3 * j + 1] - xyz[3 * i + 1];
  float dz = xyz[3 * j + 2] - xyz[3 * i + 2];
  float d2 = dx * dx + dy * dy + dz * dz + 3.0f * EPS_F;  // ref adds EPS per comp
  float d = sqrtf(d2);
  float inv_d = 1.0f / d;
  ij_s[p] = make_int2(i, j);
  unit_s[3 * p + 0] = dx * inv_d;
  unit_s[3 * p + 1] = dy * inv_d;
  unit_s[3 * p + 2] = dz * inv_d;
  float x = d * (PI_F / CUTOFF_F);
  float s1, c1;
  __sincosf(x, &s1, &c1);
  float envv = (d < CUTOFF_F) ? 0.5f * (c1 + 1.0f) : 0.0f;
  f16 tmp[32];
  float two_c = 2.0f * c1;
  float env_inv_d = envv * inv_d;
  float sp = 0.0f, sn = s1;           // Chebyshev recurrence for sin(n*x)
  tmp[0] = (f16)(sn * env_inv_d);
#pragma unroll
  for (int n = 1; n < NRBF; ++n) {
    float nx = two_c * sn - sp;
    sp = sn; sn = nx;
    tmp[n] = (f16)(sn * env_inv_d);
  }
  tmp[NRBF] = (f16)envv;
#pragma unroll
  for (int n = NRBF + 1; n < 32; ++n) tmp[n] = (f16)0.0f;
#pragma unroll
  for (int g = 0; g < 4; ++g)
    *(f16x8*)(rbf_h + (size_t)p * 32 + g * 8) = *(f16x8*)&tmp[g * 8];
}

// ---------------- pre-pack dwx = [dist_w; dist_b; 0] into MFMA B-fragment order ----------------
// dwf[l][ct][lane][q] (f16), ct=col-tile 0..23, lane 0..63, q 0..7:
//   k = (lane>>4)*8+q, col = ct*16+(lane&15)
//   val = k<20 ? dist_w[l][k][col] : (k==20 ? dist_b[l][col] : 0)
__global__ __launch_bounds__(256) void dwfrag_kernel(
    const float* __restrict__ dw, const float* __restrict__ db,
    f16* __restrict__ dwf)
{
  int idx = blockIdx.x * 256 + threadIdx.x;
  if (idx >= 3 * 24 * 64 * 8) return;
  int q = idx & 7;
  int lane = (idx >> 3) & 63;
  int ct = (idx >> 9) % 24;
  int l = idx / (24 * 64 * 8);
  int k = (lane >> 4) * 8 + q;
  int col = ct * 16 + (lane & 15);
  float val = 0.f;
  if (k < NRBF) val = dw[(size_t)l * NRBF * 384 + (size_t)k * 384 + col];
  else if (k == NRBF) val = db[(size_t)l * 384 + col];
  dwf[idx] = (f16)val;
}

// ---------------- s = embed[z] (fp32 + f16 mirror) ----------------
__global__ __launch_bounds__(256) void embed_kernel(
    const int* __restrict__ z, const float* __restrict__ embed,
    float* __restrict__ s, f16* __restrict__ s_h, int N)
{
  int idx = blockIdx.x * 256 + threadIdx.x;
  if (idx >= N * 128) return;
  int n = idx >> 7, f = idx & 127;
  float x = embed[z[n] * 128 + f];
  s[idx] = x;
  s_h[idx] = (f16)x;
}

__global__ __launch_bounds__(256) void w1t_kernel(
    const float* __restrict__ w1, f16* __restrict__ w1t)
{
  int idx = blockIdx.x * 256 + threadIdx.x;
  if (idx >= 64 * 128) return;
  int n = idx >> 7, k = idx & 127;
  w1t[idx] = (f16)w1[(size_t)k * 64 + n];
}

// ---------------- f16 MFMA GEMM ----------------
template <bool SILU, int OUT, bool AH>
__global__ __launch_bounds__(256) void gemm_kernel(
    const void* __restrict__ Ap, const float* __restrict__ W,
    const float* __restrict__ bias, const float* __restrict__ rowscale,
    void* __restrict__ Cout, int M, int N, int K)
{
  __shared__ f16 As[64][40];
  __shared__ f16 Bs[64][40];
  int t = threadIdx.x;
  int wave = t >> 6, lane = t & 63;
  int rw = wave & 1, cw = wave >> 1;
  int lr = lane & 15, quad = lane >> 4;
  int row0 = blockIdx.x * 64, col0 = blockIdx.y * 64;
  floatx4 acc[2][2] = {};
  for (int k0 = 0; k0 < K; k0 += 32) {
    if (AH) {
      const f16* A = (const f16*)Ap;
      int sm = t >> 2, sk = (t & 3) * 8;
      f16x8 av;
      if (row0 + sm < M) av = *(const f16x8*)(A + (size_t)(row0 + sm) * K + k0 + sk);
      else { for (int q = 0; q < 8; ++q) av[q] = (f16)0.0f; }
      *(f16x8*)&As[sm][sk] = av;
    } else {
      const float* A = (const float*)Ap;
#pragma unroll
      for (int u0 = 0; u0 < 2; ++u0) {
        int u = t + u0 * 256;
        int m = u >> 3, c4 = (u & 7) * 4;
        float4 av = make_float4(0.f, 0.f, 0.f, 0.f);
        if (row0 + m < M) av = *(const float4*)(A + (size_t)(row0 + m) * K + k0 + c4);
        f16x4 hv;
        hv[0] = (f16)av.x; hv[1] = (f16)av.y; hv[2] = (f16)av.z; hv[3] = (f16)av.w;
        *(f16x4*)&As[m][c4] = hv;
      }
    }
#pragma unroll
    for (int u0 = 0; u0 < 2; ++u0) {
      int u = t + u0 * 256;
      int k = u >> 4, n4 = (u & 15) * 4;
      float4 wv = *(const float4*)(W + (size_t)(k0 + k) * N + col0 + n4);
      Bs[n4 + 0][k] = (f16)wv.x;
      Bs[n4 + 1][k] = (f16)wv.y;
      Bs[n4 + 2][k] = (f16)wv.z;
      Bs[n4 + 3][k] = (f16)wv.w;
    }
    __syncthreads();
    f16x8 af[2], bfr[2];
#pragma unroll
    for (int tr = 0; tr < 2; ++tr)
      af[tr] = *(const f16x8*)&As[rw * 32 + tr * 16 + lr][quad * 8];
#pragma unroll
    for (int tc = 0; tc < 2; ++tc)
      bfr[tc] = *(const f16x8*)&Bs[cw * 32 + tc * 16 + lr][quad * 8];
#pragma unroll
    for (int tr = 0; tr < 2; ++tr)
#pragma unroll
      for (int tc = 0; tc < 2; ++tc)
        acc[tr][tc] = __builtin_amdgcn_mfma_f32_16x16x32_f16(af[tr], bfr[tc], acc[tr][tc], 0, 0, 0);
    __syncthreads();
  }
#pragma unroll
  for (int tc = 0; tc < 2; ++tc) {
    int col = col0 + cw * 32 + tc * 16 + lr;
    float bb = bias ? bias[col] : 0.0f;
#pragma unroll
    for (int tr = 0; tr < 2; ++tr) {
#pragma unroll
      for (int r = 0; r < 4; ++r) {
        int row = row0 + rw * 32 + tr * 16 + quad * 4 + r;
        if (row < M) {
          float x = acc[tr][tc][r] + bb;
          if (rowscale) x *= rowscale[row];
          if (SILU) x = silu_f(x);
          size_t o = (size_t)row * N + col;
          if (OUT == 0) ((float*)Cout)[o] = x;
          else          ((f16*)Cout)[o] = (f16)x;
        }
      }
    }
  }
}

// ---------------- dual-weight f16 MFMA GEMM: C1 = A@W1, C2 = A@W2 (fp32 A/out) ----------------
__global__ __launch_bounds__(256) void gemm_dual_kernel(
    const float* __restrict__ A, const float* __restrict__ W1,
    const float* __restrict__ W2, float* __restrict__ C1, float* __restrict__ C2,
    int M, int N, int K)
{
  __shared__ f16 As[64][40];
  __shared__ f16 Bs1[64][40];
  __shared__ f16 Bs2[64][40];
  int t = threadIdx.x;
  int wave = t >> 6, lane = t & 63;
  int rw = wave & 1, cw = wave >> 1;
  int lr = lane & 15, quad = lane >> 4;
  int row0 = blockIdx.x * 64, col0 = blockIdx.y * 64;
  floatx4 acc1[2][2] = {};
  floatx4 acc2[2][2] = {};
  for (int k0 = 0; k0 < K; k0 += 32) {
#pragma unroll
    for (int u0 = 0; u0 < 2; ++u0) {
      int u = t + u0 * 256;
      int m = u >> 3, c4 = (u & 7) * 4;
      float4 av = make_float4(0.f, 0.f, 0.f, 0.f);
      if (row0 + m < M) av = *(const float4*)(A + (size_t)(row0 + m) * K + k0 + c4);
      f16x4 hv;
      hv[0] = (f16)av.x; hv[1] = (f16)av.y; hv[2] = (f16)av.z; hv[3] = (f16)av.w;
      *(f16x4*)&As[m][c4] = hv;
    }
#pragma unroll
    for (int u0 = 0; u0 < 2; ++u0) {
      int u = t + u0 * 256;
      int k = u >> 4, n4 = (u & 15) * 4;
      float4 wv = *(const float4*)(W1 + (size_t)(k0 + k) * N + col0 + n4);
      Bs1[n4 + 0][k] = (f16)wv.x;
      Bs1[n4 + 1][k] = (f16)wv.y;
      Bs1[n4 + 2][k] = (f16)wv.z;
      Bs1[n4 + 3][k] = (f16)wv.w;
      float4 xv = *(const float4*)(W2 + (size_t)(k0 + k) * N + col0 + n4);
      Bs2[n4 + 0][k] = (f16)xv.x;
      Bs2[n4 + 1][k] = (f16)xv.y;
      Bs2[n4 + 2][k] = (f16)xv.z;
      Bs2[n4 + 3][k] = (f16)xv.w;
    }
    __syncthreads();
    f16x8 af[2], b1[2], b2[2];
#pragma unroll
    for (int tr = 0; tr < 2; ++tr)
      af[tr] = *(const f16x8*)&As[rw * 32 + tr * 16 + lr][quad * 8];
#pragma unroll
    for (int tc = 0; tc < 2; ++tc) {
      b1[tc] = *(const f16x8*)&Bs1[cw * 32 + tc * 16 + lr][quad * 8];
      b2[tc] = *(const f16x8*)&Bs2[cw * 32 + tc * 16 + lr][quad * 8];
    }
#pragma unroll
    for (int tr = 0; tr < 2; ++tr)
#pragma unroll
      for (int tc = 0; tc < 2; ++tc) {
        acc1[tr][tc] = __builtin_amdgcn_mfma_f32_16x16x32_f16(af[tr], b1[tc], acc1[tr][tc], 0, 0, 0);
        acc2[tr][tc] = __builtin_amdgcn_mfma_f32_16x16x32_f16(af[tr], b2[tc], acc2[tr][tc], 0, 0, 0);
      }
    __syncthreads();
  }
#pragma unroll
  for (int tc = 0; tc < 2; ++tc) {
    int col = col0 + cw * 32 + tc * 16 + lr;
#pragma unroll
    for (int tr = 0; tr < 2; ++tr) {
#pragma unroll
      for (int r = 0; r < 4; ++r) {
        int row = row0 + rw * 32 + tr * 16 + quad * 4 + r;
        if (row < M) {
          C1[(size_t)row * N + col] = acc1[tr][tc][r];
          C2[(size_t)row * N + col] = acc2[tr][tc][r];
        }
      }
    }
  }
}

// ---------------- MFMA-ws message kernel ----------------
// Per block (384 thr = 6 waves): tile of MEPB=32 sorted edges.
// Phase A: ws_tile[32][384] = rbfA[32x32] @ dwx[32x384] via 48 MFMAs
//          (B-fragments pre-packed per layer by dwfrag_kernel, held in 16 VGPRs/wave;
//           result stored transposed wsT[col][edge] in LDS, f16, stride 38 = 2-way free).
// Phase B: col-per-thread gather loop (round-2 mapping g=t>>7, f=t&127, col=t);
//          per-edge: 1 LDS u16 (ws) + phi gather + (g0: vh gather | g2: LDS unit);
//          flush per atom-boundary via atomicAdd (block-uniform branch).
#define MEPB 32
__global__ __launch_bounds__(384, 2) void message_kernel(
    const int2* __restrict__ ij_s, const float* __restrict__ unit_s,
    const f16* __restrict__ rbf_h, const f16* __restrict__ dwf,
    const f16* __restrict__ phi_h, const f16* __restrict__ vh,
    float* __restrict__ s, float* __restrict__ v, int E)
{
  __shared__ f16 rbfA[MEPB][40];
  __shared__ f16 wsT[384][38];
  __shared__ int2 ijL[MEPB];
  __shared__ float unitL[MEPB * 3];
  int t = threadIdx.x;
  int wave = t >> 6, lane = t & 63;
  int e_lo = blockIdx.x * MEPB;
  if (e_lo >= E) return;
  int e_hi = (e_lo + MEPB < E) ? e_lo + MEPB : E;
  int cnt = e_hi - e_lo;

  // ---- B fragments: 4 col-tiles per wave, from frag-ordered dwf ----
  f16x8 bf[4];
#pragma unroll
  for (int i = 0; i < 4; ++i) {
    int ct = wave * 4 + i;
    bf[i] = *(const f16x8*)(dwf + ((size_t)ct * 64 + lane) * 8);
  }
  // ---- stage rbf rows / ij / unit ----
  if (t < MEPB * 4) {
    int r = t >> 2, c8 = (t & 3) * 8;
    f16x8 rv;
    if (e_lo + r < E) rv = *(const f16x8*)(rbf_h + (size_t)(e_lo + r) * 32 + c8);
    else { for (int q = 0; q < 8; ++q) rv[q] = (f16)0.0f; }
    *(f16x8*)&rbfA[r][c8] = rv;
  }
  if (t < cnt) ijL[t] = ij_s[e_lo + t];
  if (t < cnt * 3) unitL[t] = unit_s[(size_t)e_lo * 3 + t];
  __syncthreads();

  // ---- MFMA: 2 row-tiles x 4 col-tiles per wave ----
  int lr = lane & 15, quad = lane >> 4;
  f16x8 af[2];
#pragma unroll
  for (int tr = 0; tr < 2; ++tr)
    af[tr] = *(const f16x8*)&rbfA[tr * 16 + lr][quad * 8];
  floatx4 acc[2][4] = {};
#pragma unroll
  for (int tr = 0; tr < 2; ++tr)
#pragma unroll
    for (int i = 0; i < 4; ++i)
      acc[tr][i] = __builtin_amdgcn_mfma_f32_16x16x32_f16(af[tr], bf[i], acc[tr][i], 0, 0, 0);
  // C/D layout: col = lane&15 (within tile), row = quad*4 + r  -> write transposed
#pragma unroll
  for (int tr = 0; tr < 2; ++tr)
#pragma unroll
    for (int i = 0; i < 4; ++i) {
      int col = (wave * 4 + i) * 16 + lr;
      int er = tr * 16 + quad * 4;
      f16x2 lo2, hi2;
      lo2[0] = (f16)acc[tr][i][0]; lo2[1] = (f16)acc[tr][i][1];
      hi2[0] = (f16)acc[tr][i][2]; hi2[1] = (f16)acc[tr][i][3];
      *(f16x2*)&wsT[col][er]     = lo2;
      *(f16x2*)&wsT[col][er + 2] = hi2;
    }
  __syncthreads();

  // ---- Phase B: gather + segment flush ----
  int g = t >> 7, f = t & 127;
  float a0 = 0.f, a1 = 0.f, a2 = 0.f;
  int prev_i = -1;
  // prologue (1-ahead pipeline for global gathers)
  int2 ij_c = ijL[0];
  f16 ph_c = phi_h[(size_t)ij_c.y * 384 + t];
  f16 vj0c = (f16)0.f, vj1c = (f16)0.f, vj2c = (f16)0.f;
  if (g == 0) {
    const f16* vp = vh + (size_t)ij_c.y * 384 + f;
    vj0c = vp[0]; vj1c = vp[128]; vj2c = vp[256];
  }
  for (int r = 0; r < cnt; ++r) {
    int rn = (r + 1 < cnt) ? r + 1 : r;
    int2 ij_n = ijL[rn];
    f16 ph_n = phi_h[(size_t)ij_n.y * 384 + t];
    f16 vj0n = (f16)0.f, vj1n = (f16)0.f, vj2n = (f16)0.f;
    if (g == 0) {
      const f16* vp = vh + (size_t)ij_n.y * 384 + f;
      vj0n = vp[0]; vj1n = vp[128]; vj2n = vp[256];
    }
    // flush on atom change (runtime block-uniform)
    if (ij_c.x != prev_i) {
      if (prev_i >= 0) {
        if (g == 1) {
          atomicAdd(s + (size_t)prev_i * 128 + f, a0);
        } else {
          float* vb = v + (size_t)prev_i * 384 + f;
          atomicAdd(vb, a0);
          atomicAdd(vb + 128, a1);
          atomicAdd(vb + 256, a2);
        }
        a0 = a1 = a2 = 0.f;
      }
      prev_i = ij_c.x;
    }
    float ws = (float)wsT[t][r];
    float inv = (float)ph_c * ws;
    if (g == 0) {
      a0 = fmaf(inv, (float)vj0c, a0);
      a1 = fmaf(inv, (float)vj1c, a1);
      a2 = fmaf(inv, (float)vj2c, a2);
    } else if (g == 1) {
      a0 += inv;
    } else {
      a0 = fmaf(inv, unitL[3 * r + 0], a0);
      a1 = fmaf(inv, unitL[3 * r + 1], a1);
      a2 = fmaf(inv, unitL[3 * r + 2], a2);
    }
    ij_c = ij_n; ph_c = ph_n;
    vj0c = vj0n; vj1c = vj1n; vj2c = vj2n;
  }
  if (prev_i >= 0) {
    if (g == 1) {
      atomicAdd(s + (size_t)prev_i * 128 + f, a0);
    } else {
      float* vb = v + (size_t)prev_i * 384 + f;
      atomicAdd(vb, a0);
      atomicAdd(vb + 128, a1);
      atomicAdd(vb + 256, a2);
    }
  }
}

// ---------------- s_stack = [s, ||v_v||] (f16 out) ----------------
__global__ __launch_bounds__(256) void stack_kernel(
    const float* __restrict__ s, const float* __restrict__ v_v,
    f16* __restrict__ s_stack, int N)
{
  int idx = blockIdx.x * 256 + threadIdx.x;
  if (idx >= N * 128) return;
  int n = idx >> 7, g = idx & 127;
  float a = v_v[(size_t)n * 384 + g];
  float b = v_v[(size_t)n * 384 + 128 + g];
  float c = v_v[(size_t)n * 384 + 256 + g];
  s_stack[(size_t)n * 256 + g] = (f16)s[idx];
  s_stack[(size_t)n * 256 + 128 + g] = (f16)sqrtf(a * a + b * b + c * c + EPS_F);
}

// ---------------- gated update of s, v (+ f16 mirrors for next-layer reads) ----------------
__global__ __launch_bounds__(256) void apply_kernel(
    float* __restrict__ s, f16* __restrict__ s_h,
    float* __restrict__ v, f16* __restrict__ v_h,
    const float* __restrict__ u_v, const float* __restrict__ v_v,
    const float* __restrict__ sp, int N)
{
  int idx = blockIdx.x * 256 + threadIdx.x;
  if (idx >= N * 128) return;
  int n = idx >> 7, g = idx & 127;
  float sp0 = sp[(size_t)n * 384 + g];
  float sp1 = sp[(size_t)n * 384 + 128 + g];
  float sp2 = sp[(size_t)n * 384 + 256 + g];
  float dot = 0.f;
#pragma unroll
  for (int c = 0; c < 3; ++c) {
    size_t o = (size_t)n * 384 + c * 128 + g;
    float uv = u_v[o];
    float vn = fmaf(uv, sp0, v[o]);
    v[o] = vn;
    v_h[o] = (f16)vn;
    dot = fmaf(uv, v_v[o], dot);
  }
  float sn = s[idx] + dot * sp1 + sp2;
  s[idx] = sn;
  s_h[idx] = (f16)sn;
}

// ---------------- fused f16 MFMA readout (unsorted edges; register-prefetched gathers) ----------------
__global__ __launch_bounds__(256) void readout_gemm_kernel(
    const int* __restrict__ nbr, const float* __restrict__ xyz,
    const f16* __restrict__ s_h, const f16* __restrict__ w1t,
    const float* __restrict__ b1, const float* __restrict__ w2,
    const float* __restrict__ b2, float* __restrict__ out, int E)
{
  __shared__ f16 As[64][40];
  __shared__ f16 Bs[64][40];
  __shared__ float red[2][64];
  __shared__ int ijc[64][2];
  int t = threadIdx.x;
  int wave = t >> 6, lane = t & 63;
  int rw = wave & 1, cw = wave >> 1;
  int lr = lane & 15, quad = lane >> 4;
  int e0b = blockIdx.x * 64;
  if (t < 64) {
    int e = e0b + t;
    if (e < E) { ijc[t][0] = nbr[2 * e]; ijc[t][1] = nbr[2 * e + 1]; }
    else { ijc[t][0] = 0; ijc[t][1] = 0; }
  }
  __syncthreads();
  int m = t >> 2;             // one row (edge) per thread
  int c8 = (t & 3) * 8;       // 8 features within 32-k window
  int im = ijc[m][0], jm = ijc[m][1];
  bool okm = (e0b + m) < E;
  // prefetch all 8 row-segments (4 windows x i/j) - independent loads in flight
  f16x8 xa[4], ya[4];
  if (okm) {
#pragma unroll
    for (int w = 0; w < 4; ++w) {
      xa[w] = *(const f16x8*)(s_h + (size_t)im * 128 + w * 32 + c8);
      ya[w] = *(const f16x8*)(s_h + (size_t)jm * 128 + w * 32 + c8);
    }
  } else {
#pragma unroll
    for (int w = 0; w < 4; ++w)
      for (int q = 0; q < 8; ++q) { xa[w][q] = (f16)0.0f; ya[w][q] = (f16)0.0f; }
  }
  floatx4 acc[2][2] = {};
#pragma unroll
  for (int w = 0; w < 4; ++w) {
    *(f16x8*)&As[m][c8] = xa[w] + ya[w];
    {
      int sm = t >> 2, sk = (t & 3) * 8;
      *(f16x8*)&Bs[sm][sk] = *(const f16x8*)(w1t + (size_t)sm * 128 + w * 32 + sk);
    }
    __syncthreads();
    f16x8 af[2], bfr[2];
#pragma unroll
    for (int tr = 0; tr < 2; ++tr)
      af[tr] = *(const f16x8*)&As[rw * 32 + tr * 16 + lr][quad * 8];
#pragma unroll
    for (int tc = 0; tc < 2; ++tc)
      bfr[tc] = *(const f16x8*)&Bs[cw * 32 + tc * 16 + lr][quad * 8];
#pragma unroll
    for (int tr = 0; tr < 2; ++tr)
#pragma unroll
      for (int tc = 0; tc < 2; ++tc)
        acc[tr][tc] = __builtin_amdgcn_mfma_f32_16x16x32_f16(af[tr], bfr[tc], acc[tr][tc], 0, 0, 0);
    __syncthreads();
  }
  float b1v[2], w2v[2];
#pragma unroll
  for (int tc = 0; tc < 2; ++tc) {
    int col = cw * 32 + tc * 16 + lr;
    b1v[tc] = b1[col];
    w2v[tc] = w2[col];
  }
#pragma unroll
  for (int tr = 0; tr < 2; ++tr) {
#pragma unroll
    for (int r = 0; r < 4; ++r) {
      float p = 0.f;
#pragma unroll
      for (int tc = 0; tc < 2; ++tc)
        p += silu_f(acc[tr][tc][r] + b1v[tc]) * w2v[tc];
#pragma unroll
      for (int ofs = 1; ofs < 16; ofs <<= 1) p += __shfl_xor(p, ofs, 64);
      if (lr == 0) red[cw][rw * 32 + tr * 16 + quad * 4 + r] = p;
    }
  }
  __syncthreads();
  if (t < 64) {
    int e = e0b + t;
    if (e < E) {
      float fs = red[0][t] + red[1][t] + b2[0];
      int i = ijc[t][0], j = ijc[t][1];
      float dx = xyz[3 * i + 0] - xyz[3 * j + 0];
      float dy = xyz[3 * i + 1] - xyz[3 * j + 1];
      float dz = xyz[3 * i + 2] - xyz[3 * j + 2];
      float dis = sqrtf(dx * dx + dy * dy + dz * dz);  // no EPS here (matches ref)
      float sc = fs / dis;
      float fx = sc * dx, fy = sc * dy, fz = sc * dz;
      atomicAdd(out + (size_t)i * 3 + 0, fx);
      atomicAdd(out + (size_t)i * 3 + 1, fy);
      atomicAdd(out + (size_t)i * 3 + 2, fz);
      atomicAdd(out + (size_t)j * 3 + 0, -fx);
      atomicAdd(out + (size_t)j * 3 + 1, -fy);
      atomicAdd(out + (size_t)j * 3 + 2, -fz);
    }
  }
}

extern "C" void kernel_launch(void* const* d_in, const int* in_sizes, int n_in,
                              void* d_out, int out_size, void* d_ws, size_t ws_size,
                              hipStream_t stream) {
  const float* xyz    = (const float*)d_in[0];
  const int*   z      = (const int*)d_in[1];
  const int*   nbr    = (const int*)d_in[2];
  const float* embed  = (const float*)d_in[3];
  const float* msg_w1 = (const float*)d_in[4];
  const float* msg_b1 = (const float*)d_in[5];
  const float* msg_w2 = (const float*)d_in[6];
  const float* msg_b2 = (const float*)d_in[7];
  const float* dist_w = (const float*)d_in[8];
  const float* dist_b = (const float*)d_in[9];
  const float* upd_u  = (const float*)d_in[10];
  const float* upd_v  = (const float*)d_in[11];
  const float* upd_w1 = (const float*)d_in[12];
  const float* upd_b1 = (const float*)d_in[13];
  const float* upd_w2 = (const float*)d_in[14];
  const float* upd_b2 = (const float*)d_in[15];
  const float* ero_w1 = (const float*)d_in[16];
  const float* ero_b1 = (const float*)d_in[17];
  const float* ero_w2 = (const float*)d_in[18];
  const float* ero_b2 = (const float*)d_in[19];

  const int N = in_sizes[1];      // 10000
  const int E = in_sizes[2] / 2;  // 160000
  const int L = 3;

  char* ws = (char*)d_ws;
  size_t off = 0;
  auto alloc = [&](size_t bytes) -> void* {
    void* p = ws + off;
    off += (bytes + 255) & ~(size_t)255;
    return p;
  };
  float* unit_s = (float*)alloc((size_t)E * 3 * 4);
  f16*   rbf_h  = (f16*)alloc((size_t)E * 32 * 2);
  int2*  ij_s   = (int2*)alloc((size_t)E * 8);
  int*   order  = (int*)alloc((size_t)E * 4);
  float* s      = (float*)alloc((size_t)N * 128 * 4);
  f16*   s_h    = (f16*)alloc((size_t)N * 128 * 2);
  float* vA     = (float*)alloc((size_t)N * 384 * 4);
  f16*   vhA    = (f16*)alloc((size_t)N * 384 * 2);
  f16*   phi_h  = (f16*)alloc((size_t)N * 384 * 2);
  f16*   w1t    = (f16*)alloc((size_t)64 * 128 * 2);
  f16*   dwf    = (f16*)alloc((size_t)3 * 24 * 64 * 8 * 2);
  int*   histx  = (int*)alloc((size_t)(N + 1) * 4);
  int*   startp = (int*)alloc((size_t)(N + 1) * 4);
  int*   cursor = (int*)alloc((size_t)N * 4);
  float* u_v    = (float*)alloc((size_t)N * 384 * 4);
  float* v_v    = (float*)alloc((size_t)N * 384 * 4);
  float* sp     = (float*)alloc((size_t)N * 384 * 4);
  f16*   sstk_h = (f16*)alloc((size_t)N * 256 * 2);
  f16*   h_h    = (f16*)alloc((size_t)N * 128 * 2);

  auto cdiv = [](int a, int b) { return (a + b - 1) / b; };

  // ---- setup: deterministic CSR + weight pre-pack ----
  hipMemsetAsync(vA, 0, (size_t)N * 384 * 4, stream);
  hipMemsetAsync(vhA, 0, (size_t)N * 384 * 2, stream);
  hipMemsetAsync(histx, 0, (size_t)(N + 1) * 4, stream);
  hist_kernel<<<cdiv(E, 256), 256, 0, stream>>>(nbr, histx, E);
  scan_kernel<<<1, 1024, 0, stream>>>(histx, startp, cursor, N);
  scatter_id_kernel<<<cdiv(E, 256), 256, 0, stream>>>(nbr, cursor, order, E);
  segsort_kernel<<<cdiv(N, 4), 256, 0, stream>>>(order, startp, N);
  geom_fill_kernel<<<cdiv(E, 256), 256, 0, stream>>>(
      order, nbr, xyz, ij_s, unit_s, rbf_h, E);
  embed_kernel<<<cdiv(N * 128, 256), 256, 0, stream>>>(z, embed, s, s_h, N);
  w1t_kernel<<<cdiv(64 * 128, 256), 256, 0, stream>>>(ero_w1, w1t);
  dwfrag_kernel<<<cdiv(3 * 24 * 64 * 8, 256), 256, 0, stream>>>(dist_w, dist_b, dwf);

  for (int l = 0; l < L; ++l) {
    // phi = silu(s @ msg_w1 + b1) @ msg_w2 + b2  -> f16 (A read from f16 mirror)
    gemm_kernel<true, 1, true><<<dim3(cdiv(N, 64), 2), 256, 0, stream>>>(
        s_h, msg_w1 + (size_t)l * 128 * 128, msg_b1 + (size_t)l * 128, nullptr, h_h, N, 128, 128);
    gemm_kernel<false, 1, true><<<dim3(cdiv(N, 64), 6), 256, 0, stream>>>(
        h_h, msg_w2 + (size_t)l * 128 * 384, msg_b2 + (size_t)l * 384, nullptr, phi_h, N, 384, 128);
    // MFMA-ws message; atomic flush into s / v (in place)
    message_kernel<<<cdiv(E, MEPB), 384, 0, stream>>>(
        ij_s, unit_s, rbf_h, dwf + (size_t)l * 24 * 64 * 8,
        phi_h, vhA, s, vA, E);
    // update block
    gemm_dual_kernel<<<dim3(cdiv(N * 3, 64), 2), 256, 0, stream>>>(
        vA, upd_u + (size_t)l * 128 * 128, upd_v + (size_t)l * 128 * 128,
        u_v, v_v, N * 3, 128, 128);
    stack_kernel<<<cdiv(N * 128, 256), 256, 0, stream>>>(s, v_v, sstk_h, N);
    gemm_kernel<true, 1, true><<<dim3(cdiv(N, 64), 2), 256, 0, stream>>>(
        sstk_h, upd_w1 + (size_t)l * 256 * 128, upd_b1 + (size_t)l * 128, nullptr, h_h, N, 128, 256);
    gemm_kernel<false, 0, true><<<dim3(cdiv(N, 64), 6), 256, 0, stream>>>(
        h_h, upd_w2 + (size_t)l * 128 * 384, upd_b2 + (size_t)l * 384, nullptr, sp, N, 384, 128);
    apply_kernel<<<cdiv(N * 128, 256), 256, 0, stream>>>(
        s, s_h, vA, vhA, u_v, v_v, sp, N);
  }

  // fused f16 MFMA readout (unsorted edges, register-prefetched gathers)
  hipMemsetAsync(d_out, 0, (size_t)out_size * 4, stream);
  readout_gemm_kernel<<<cdiv(E, 64), 256, 0, stream>>>(
      nbr, xyz, s_h, w1t, ero_b1, ero_w2, ero_b2, (float*)d_out, E);
}

// Round 4
// 718.550 us; speedup vs baseline: 1.4214x; 1.0698x over previous
//
#include <hip/hip_runtime.h>
#include <math.h>

#define EPS_F 1e-15f
#define NRBF 20
#define CUTOFF_F 5.0f
#define PI_F 3.14159265358979323846f

typedef unsigned short u16;
typedef _Float16 f16;
typedef f16 f16x8 __attribute__((ext_vector_type(8)));
typedef f16 f16x4 __attribute__((ext_vector_type(4)));
typedef f16 f16x2 __attribute__((ext_vector_type(2)));
typedef float floatx4 __attribute__((ext_vector_type(4)));

__device__ __forceinline__ float silu_f(float x) { return x / (1.0f + expf(-x)); }

// ---------------- counting sort: histogram + scan ----------------
__global__ __launch_bounds__(256) void hist_kernel(
    const int* __restrict__ nbr, int* __restrict__ hist, int E)
{
  int e = blockIdx.x * 256 + threadIdx.x;
  if (e >= E) return;
  atomicAdd(hist + nbr[2 * e], 1);
}

// single-block exclusive scan, wave-shfl based (few barriers)
__global__ __launch_bounds__(1024) void scan_kernel(
    const int* __restrict__ hist, int* __restrict__ start,
    int* __restrict__ cursor, int N)
{
  __shared__ int wsum[16];
  __shared__ int carry_s;
  int tid = threadIdx.x;
  int lane = tid & 63, wid = tid >> 6;
  if (tid == 0) carry_s = 0;
  __syncthreads();
  for (int base = 0; base < N; base += 1024) {
    int x = (base + tid < N) ? hist[base + tid] : 0;
    int v = x;
#pragma unroll
    for (int o = 1; o < 64; o <<= 1) {
      int t2 = __shfl_up(v, o, 64);
      if (lane >= o) v += t2;
    }
    if (lane == 63) wsum[wid] = v;
    __syncthreads();
    if (tid < 16) {
      int w = wsum[tid];
#pragma unroll
      for (int o = 1; o < 16; o <<= 1) {
        int t2 = __shfl_up(w, o, 64);
        if (tid >= o) w += t2;
      }
      wsum[tid] = w;
    }
    __syncthreads();
    int wbase = (wid == 0) ? 0 : wsum[wid - 1];
    int incl = v + wbase;
    int carry = carry_s;
    if (base + tid < N) {
      int ex = carry + incl - x;
      start[base + tid] = ex;
      cursor[base + tid] = ex;
    }
    __syncthreads();
    if (tid == 1023) carry_s = carry + incl;
    __syncthreads();
  }
  if (tid == 0) start[N] = carry_s;
}

// ---------------- scatter edge IDs ----------------
__global__ __launch_bounds__(256) void scatter_id_kernel(
    const int* __restrict__ nbr, int* __restrict__ cursor,
    int* __restrict__ order, int E)
{
  int e = blockIdx.x * 256 + threadIdx.x;
  if (e >= E) return;
  int pos = atomicAdd(cursor + nbr[2 * e], 1);
  order[pos] = e;
}

// ---------------- canonicalize: wave rank-sort of each atom's segment ----------------
__global__ __launch_bounds__(256) void segsort_kernel(
    int* __restrict__ order, const int* __restrict__ start, int N)
{
  int wi = blockIdx.x * 4 + (threadIdx.x >> 6);
  int lane = threadIdx.x & 63;
  if (wi >= N) return;
  int s0 = start[wi], s1 = start[wi + 1];
  int len = s1 - s0;
  if (len <= 1) return;
  if (len <= 64) {
    int id = (lane < len) ? order[s0 + lane] : 0x7FFFFFFF;
    int rank = 0;
#pragma unroll
    for (int k = 0; k < 64; ++k) {
      int other = __shfl(id, k, 64);
      rank += (other < id) ? 1 : 0;
    }
    if (lane < len) order[s0 + rank] = id;
  } else if (lane == 0) {
    for (int a = s0 + 1; a < s1; ++a) {
      int key = order[a];
      int b = a - 1;
      while (b >= s0 && order[b] > key) { order[b + 1] = order[b]; --b; }
      order[b + 1] = key;
    }
  }
}

// ---------------- geometry gather-fill (deterministic) ----------------
// rbf_h row layout (32 f16): slots 0..19 = sin(k_n d)/d * env   (env pre-folded)
//                            slot  20    = env
//                            slots 21..31 = 0
// So w_s col = dot(rbf_row[0..20], [dist_w; dist_b] col).
__global__ __launch_bounds__(256) void geom_fill_kernel(
    const int* __restrict__ order, const int* __restrict__ nbr,
    const float* __restrict__ xyz, int2* __restrict__ ij_s,
    float* __restrict__ unit_s, f16* __restrict__ rbf_h, int E)
{
  int p = blockIdx.x * 256 + threadIdx.x;
  if (p >= E) return;
  int e = order[p];
  int i = nbr[2 * e], j = nbr[2 * e + 1];
  float dx = xyz[3 * j + 0] - xyz[3 * i + 0];
  float dy = xyz[3 * j + 1] - xyz[3 * i + 1];
  float dz = xyz[3 * j + 2] - xyz[3 * i + 2];
  float d2 = dx * dx + dy * dy + dz * dz + 3.0f * EPS_F;  // ref adds EPS per comp
  float d = sqrtf(d2);
  float inv_d = 1.0f / d;
  ij_s[p] = make_int2(i, j);
  unit_s[3 * p + 0] = dx * inv_d;
  unit_s[3 * p + 1] = dy * inv_d;
  unit_s[3 * p + 2] = dz * inv_d;
  float x = d * (PI_F / CUTOFF_F);
  float s1, c1;
  __sincosf(x, &s1, &c1);
  float envv = (d < CUTOFF_F) ? 0.5f * (c1 + 1.0f) : 0.0f;
  f16 tmp[32];
  float two_c = 2.0f * c1;
  float env_inv_d = envv * inv_d;
  float sp = 0.0f, sn = s1;           // Chebyshev recurrence for sin(n*x)
  tmp[0] = (f16)(sn * env_inv_d);
#pragma unroll
  for (int n = 1; n < NRBF; ++n) {
    float nx = two_c * sn - sp;
    sp = sn; sn = nx;
    tmp[n] = (f16)(sn * env_inv_d);
  }
  tmp[NRBF] = (f16)envv;
#pragma unroll
  for (int n = NRBF + 1; n < 32; ++n) tmp[n] = (f16)0.0f;
#pragma unroll
  for (int g = 0; g < 4; ++g)
    *(f16x8*)(rbf_h + (size_t)p * 32 + g * 8) = *(f16x8*)&tmp[g * 8];
}

// ---------------- pre-pack dwx = [dist_w; dist_b; 0] into MFMA B-fragment order ----------------
// dwf[l][ct][lane][q] (f16), ct=col-tile 0..23, lane 0..63, q 0..7:
//   k = (lane>>4)*8+q, col = ct*16+(lane&15)
//   val = k<20 ? dist_w[l][k][col] : (k==20 ? dist_b[l][col] : 0)
__global__ __launch_bounds__(256) void dwfrag_kernel(
    const float* __restrict__ dw, const float* __restrict__ db,
    f16* __restrict__ dwf)
{
  int idx = blockIdx.x * 256 + threadIdx.x;
  if (idx >= 3 * 24 * 64 * 8) return;
  int q = idx & 7;
  int lane = (idx >> 3) & 63;
  int ct = (idx >> 9) % 24;
  int l = idx / (24 * 64 * 8);
  int k = (lane >> 4) * 8 + q;
  int col = ct * 16 + (lane & 15);
  float val = 0.f;
  if (k < NRBF) val = dw[(size_t)l * NRBF * 384 + (size_t)k * 384 + col];
  else if (k == NRBF) val = db[(size_t)l * 384 + col];
  dwf[idx] = (f16)val;
}

// ---------------- s = embed[z] (fp32 + f16 mirror) ----------------
__global__ __launch_bounds__(256) void embed_kernel(
    const int* __restrict__ z, const float* __restrict__ embed,
    float* __restrict__ s, f16* __restrict__ s_h, int N)
{
  int idx = blockIdx.x * 256 + threadIdx.x;
  if (idx >= N * 128) return;
  int n = idx >> 7, f = idx & 127;
  float x = embed[z[n] * 128 + f];
  s[idx] = x;
  s_h[idx] = (f16)x;
}

__global__ __launch_bounds__(256) void w1t_kernel(
    const float* __restrict__ w1, f16* __restrict__ w1t)
{
  int idx = blockIdx.x * 256 + threadIdx.x;
  if (idx >= 64 * 128) return;
  int n = idx >> 7, k = idx & 127;
  w1t[idx] = (f16)w1[(size_t)k * 64 + n];
}

// ---------------- f16 MFMA GEMM ----------------
template <bool SILU, int OUT, bool AH>
__global__ __launch_bounds__(256) void gemm_kernel(
    const void* __restrict__ Ap, const float* __restrict__ W,
    const float* __restrict__ bias, const float* __restrict__ rowscale,
    void* __restrict__ Cout, int M, int N, int K)
{
  __shared__ f16 As[64][40];
  __shared__ f16 Bs[64][40];
  int t = threadIdx.x;
  int wave = t >> 6, lane = t & 63;
  int rw = wave & 1, cw = wave >> 1;
  int lr = lane & 15, quad = lane >> 4;
  int row0 = blockIdx.x * 64, col0 = blockIdx.y * 64;
  floatx4 acc[2][2] = {};
  for (int k0 = 0; k0 < K; k0 += 32) {
    if (AH) {
      const f16* A = (const f16*)Ap;
      int sm = t >> 2, sk = (t & 3) * 8;
      f16x8 av;
      if (row0 + sm < M) av = *(const f16x8*)(A + (size_t)(row0 + sm) * K + k0 + sk);
      else { for (int q = 0; q < 8; ++q) av[q] = (f16)0.0f; }
      *(f16x8*)&As[sm][sk] = av;
    } else {
      const float* A = (const float*)Ap;
#pragma unroll
      for (int u0 = 0; u0 < 2; ++u0) {
        int u = t + u0 * 256;
        int m = u >> 3, c4 = (u & 7) * 4;
        float4 av = make_float4(0.f, 0.f, 0.f, 0.f);
        if (row0 + m < M) av = *(const float4*)(A + (size_t)(row0 + m) * K + k0 + c4);
        f16x4 hv;
        hv[0] = (f16)av.x; hv[1] = (f16)av.y; hv[2] = (f16)av.z; hv[3] = (f16)av.w;
        *(f16x4*)&As[m][c4] = hv;
      }
    }
#pragma unroll
    for (int u0 = 0; u0 < 2; ++u0) {
      int u = t + u0 * 256;
      int k = u >> 4, n4 = (u & 15) * 4;
      float4 wv = *(const float4*)(W + (size_t)(k0 + k) * N + col0 + n4);
      Bs[n4 + 0][k] = (f16)wv.x;
      Bs[n4 + 1][k] = (f16)wv.y;
      Bs[n4 + 2][k] = (f16)wv.z;
      Bs[n4 + 3][k] = (f16)wv.w;
    }
    __syncthreads();
    f16x8 af[2], bfr[2];
#pragma unroll
    for (int tr = 0; tr < 2; ++tr)
      af[tr] = *(const f16x8*)&As[rw * 32 + tr * 16 + lr][quad * 8];
#pragma unroll
    for (int tc = 0; tc < 2; ++tc)
      bfr[tc] = *(const f16x8*)&Bs[cw * 32 + tc * 16 + lr][quad * 8];
#pragma unroll
    for (int tr = 0; tr < 2; ++tr)
#pragma unroll
      for (int tc = 0; tc < 2; ++tc)
        acc[tr][tc] = __builtin_amdgcn_mfma_f32_16x16x32_f16(af[tr], bfr[tc], acc[tr][tc], 0, 0, 0);
    __syncthreads();
  }
#pragma unroll
  for (int tc = 0; tc < 2; ++tc) {
    int col = col0 + cw * 32 + tc * 16 + lr;
    float bb = bias ? bias[col] : 0.0f;
#pragma unroll
    for (int tr = 0; tr < 2; ++tr) {
#pragma unroll
      for (int r = 0; r < 4; ++r) {
        int row = row0 + rw * 32 + tr * 16 + quad * 4 + r;
        if (row < M) {
          float x = acc[tr][tc][r] + bb;
          if (rowscale) x *= rowscale[row];
          if (SILU) x = silu_f(x);
          size_t o = (size_t)row * N + col;
          if (OUT == 0) ((float*)Cout)[o] = x;
          else          ((f16*)Cout)[o] = (f16)x;
        }
      }
    }
  }
}

// ---------------- dual-weight f16 MFMA GEMM: C1 = A@W1, C2 = A@W2 (fp32 A/out) ----------------
__global__ __launch_bounds__(256) void gemm_dual_kernel(
    const float* __restrict__ A, const float* __restrict__ W1,
    const float* __restrict__ W2, float* __restrict__ C1, float* __restrict__ C2,
    int M, int N, int K)
{
  __shared__ f16 As[64][40];
  __shared__ f16 Bs1[64][40];
  __shared__ f16 Bs2[64][40];
  int t = threadIdx.x;
  int wave = t >> 6, lane = t & 63;
  int rw = wave & 1, cw = wave >> 1;
  int lr = lane & 15, quad = lane >> 4;
  int row0 = blockIdx.x * 64, col0 = blockIdx.y * 64;
  floatx4 acc1[2][2] = {};
  floatx4 acc2[2][2] = {};
  for (int k0 = 0; k0 < K; k0 += 32) {
#pragma unroll
    for (int u0 = 0; u0 < 2; ++u0) {
      int u = t + u0 * 256;
      int m = u >> 3, c4 = (u & 7) * 4;
      float4 av = make_float4(0.f, 0.f, 0.f, 0.f);
      if (row0 + m < M) av = *(const float4*)(A + (size_t)(row0 + m) * K + k0 + c4);
      f16x4 hv;
      hv[0] = (f16)av.x; hv[1] = (f16)av.y; hv[2] = (f16)av.z; hv[3] = (f16)av.w;
      *(f16x4*)&As[m][c4] = hv;
    }
#pragma unroll
    for (int u0 = 0; u0 < 2; ++u0) {
      int u = t + u0 * 256;
      int k = u >> 4, n4 = (u & 15) * 4;
      float4 wv = *(const float4*)(W1 + (size_t)(k0 + k) * N + col0 + n4);
      Bs1[n4 + 0][k] = (f16)wv.x;
      Bs1[n4 + 1][k] = (f16)wv.y;
      Bs1[n4 + 2][k] = (f16)wv.z;
      Bs1[n4 + 3][k] = (f16)wv.w;
      float4 xv = *(const float4*)(W2 + (size_t)(k0 + k) * N + col0 + n4);
      Bs2[n4 + 0][k] = (f16)xv.x;
      Bs2[n4 + 1][k] = (f16)xv.y;
      Bs2[n4 + 2][k] = (f16)xv.z;
      Bs2[n4 + 3][k] = (f16)xv.w;
    }
    __syncthreads();
    f16x8 af[2], b1[2], b2[2];
#pragma unroll
    for (int tr = 0; tr < 2; ++tr)
      af[tr] = *(const f16x8*)&As[rw * 32 + tr * 16 + lr][quad * 8];
#pragma unroll
    for (int tc = 0; tc < 2; ++tc) {
      b1[tc] = *(const f16x8*)&Bs1[cw * 32 + tc * 16 + lr][quad * 8];
      b2[tc] = *(const f16x8*)&Bs2[cw * 32 + tc * 16 + lr][quad * 8];
    }
#pragma unroll
    for (int tr = 0; tr < 2; ++tr)
#pragma unroll
      for (int tc = 0; tc < 2; ++tc) {
        acc1[tr][tc] = __builtin_amdgcn_mfma_f32_16x16x32_f16(af[tr], b1[tc], acc1[tr][tc], 0, 0, 0);
        acc2[tr][tc] = __builtin_amdgcn_mfma_f32_16x16x32_f16(af[tr], b2[tc], acc2[tr][tc], 0, 0, 0);
      }
    __syncthreads();
  }
#pragma unroll
  for (int tc = 0; tc < 2; ++tc) {
    int col = col0 + cw * 32 + tc * 16 + lr;
#pragma unroll
    for (int tr = 0; tr < 2; ++tr) {
#pragma unroll
      for (int r = 0; r < 4; ++r) {
        int row = row0 + rw * 32 + tr * 16 + quad * 4 + r;
        if (row < M) {
          C1[(size_t)row * N + col] = acc1[tr][tc][r];
          C2[(size_t)row * N + col] = acc2[tr][tc][r];
        }
      }
    }
  }
}

// ---------------- MFMA-ws message kernel ----------------
// Phase A: ws_tile[32][384] = rbfA @ dwx via 48 MFMAs (unchanged from r3).
// Phase B: gather loop with 8-DEEP register pipeline. All gather addresses
// (ijL[0..31]) are known after staging, so slot-k's next load issues right
// after slot-k is consumed -> 8 independent loads in flight per thread
// (r3 had 1 -> each iter stalled ~300-600cy on L2/L3 latency; counters:
// VALUBusy 29%, HBM 18%, occ 50% = latency-bound). Named slots, not
// arrays (runtime-indexed ext-vector arrays go to scratch).
#define MEPB 32
__global__ __launch_bounds__(384, 6) void message_kernel(
    const int2* __restrict__ ij_s, const float* __restrict__ unit_s,
    const f16* __restrict__ rbf_h, const f16* __restrict__ dwf,
    const f16* __restrict__ phi_h, const f16* __restrict__ vh,
    float* __restrict__ s, float* __restrict__ v, int E)
{
  __shared__ f16 rbfA[MEPB][40];
  __shared__ f16 wsT[384][38];
  __shared__ int2 ijL[MEPB];
  __shared__ float unitL[MEPB * 3];
  int t = threadIdx.x;
  int wave = t >> 6, lane = t & 63;
  int e_lo = blockIdx.x * MEPB;
  if (e_lo >= E) return;
  int e_hi = (e_lo + MEPB < E) ? e_lo + MEPB : E;
  int cnt = e_hi - e_lo;

  // ---- B fragments: 4 col-tiles per wave, from frag-ordered dwf ----
  f16x8 bf[4];
#pragma unroll
  for (int i = 0; i < 4; ++i) {
    int ct = wave * 4 + i;
    bf[i] = *(const f16x8*)(dwf + ((size_t)ct * 64 + lane) * 8);
  }
  // ---- stage rbf rows / ij / unit ----
  if (t < MEPB * 4) {
    int r = t >> 2, c8 = (t & 3) * 8;
    f16x8 rv;
    if (e_lo + r < E) rv = *(const f16x8*)(rbf_h + (size_t)(e_lo + r) * 32 + c8);
    else { for (int q = 0; q < 8; ++q) rv[q] = (f16)0.0f; }
    *(f16x8*)&rbfA[r][c8] = rv;
  }
  if (t < cnt) ijL[t] = ij_s[e_lo + t];
  if (t < cnt * 3) unitL[t] = unit_s[(size_t)e_lo * 3 + t];
  __syncthreads();

  // ---- MFMA: 2 row-tiles x 4 col-tiles per wave ----
  int lr = lane & 15, quad = lane >> 4;
  f16x8 af[2];
#pragma unroll
  for (int tr = 0; tr < 2; ++tr)
    af[tr] = *(const f16x8*)&rbfA[tr * 16 + lr][quad * 8];
  floatx4 acc[2][4] = {};
#pragma unroll
  for (int tr = 0; tr < 2; ++tr)
#pragma unroll
    for (int i = 0; i < 4; ++i)
      acc[tr][i] = __builtin_amdgcn_mfma_f32_16x16x32_f16(af[tr], bf[i], acc[tr][i], 0, 0, 0);
  // C/D layout: col = lane&15 (within tile), row = quad*4 + r  -> write transposed
#pragma unroll
  for (int tr = 0; tr < 2; ++tr)
#pragma unroll
    for (int i = 0; i < 4; ++i) {
      int col = (wave * 4 + i) * 16 + lr;
      int er = tr * 16 + quad * 4;
      f16x2 lo2, hi2;
      lo2[0] = (f16)acc[tr][i][0]; lo2[1] = (f16)acc[tr][i][1];
      hi2[0] = (f16)acc[tr][i][2]; hi2[1] = (f16)acc[tr][i][3];
      *(f16x2*)&wsT[col][er]     = lo2;
      *(f16x2*)&wsT[col][er + 2] = hi2;
    }
  __syncthreads();

  // ---- Phase B: gather + segment flush, 8-deep pipeline ----
  int g = t >> 7, f = t & 127;
  float a0 = 0.f, a1 = 0.f, a2 = 0.f;
  int prev_i = -1;
  f16 ph_0 = (f16)0.f, ph_1 = (f16)0.f, ph_2 = (f16)0.f, ph_3 = (f16)0.f;
  f16 ph_4 = (f16)0.f, ph_5 = (f16)0.f, ph_6 = (f16)0.f, ph_7 = (f16)0.f;
  f16 vj0_0 = (f16)0.f, vj1_0 = (f16)0.f, vj2_0 = (f16)0.f;
  f16 vj0_1 = (f16)0.f, vj1_1 = (f16)0.f, vj2_1 = (f16)0.f;
  f16 vj0_2 = (f16)0.f, vj1_2 = (f16)0.f, vj2_2 = (f16)0.f;
  f16 vj0_3 = (f16)0.f, vj1_3 = (f16)0.f, vj2_3 = (f16)0.f;
  f16 vj0_4 = (f16)0.f, vj1_4 = (f16)0.f, vj2_4 = (f16)0.f;
  f16 vj0_5 = (f16)0.f, vj1_5 = (f16)0.f, vj2_5 = (f16)0.f;
  f16 vj0_6 = (f16)0.f, vj1_6 = (f16)0.f, vj2_6 = (f16)0.f;
  f16 vj0_7 = (f16)0.f, vj1_7 = (f16)0.f, vj2_7 = (f16)0.f;

#define MK_LOAD(S, RR) do { int rv_ = (RR); if (rv_ < cnt) {                  \
    int jj_ = ijL[rv_].y;                                                      \
    ph_##S = phi_h[(size_t)jj_ * 384 + t];                                     \
    if (g == 0) { const f16* vp_ = vh + (size_t)jj_ * 384 + f;                 \
      vj0_##S = vp_[0]; vj1_##S = vp_[128]; vj2_##S = vp_[256]; }              \
  } } while (0)

#define MK_PROC(S, RR) do { int rv_ = (RR); if (rv_ < cnt) {                   \
    int ix_ = ijL[rv_].x;                                                      \
    if (ix_ != prev_i) {                                                       \
      if (prev_i >= 0) {                                                       \
        if (g == 1) atomicAdd(s + (size_t)prev_i * 128 + f, a0);               \
        else { float* vb_ = v + (size_t)prev_i * 384 + f;                      \
          atomicAdd(vb_, a0); atomicAdd(vb_ + 128, a1); atomicAdd(vb_ + 256, a2); } \
        a0 = a1 = a2 = 0.f; }                                                  \
      prev_i = ix_; }                                                          \
    float ws_ = (float)wsT[t][rv_];                                            \
    float inv_ = (float)ph_##S * ws_;                                          \
    if (g == 0) { a0 = fmaf(inv_, (float)vj0_##S, a0);                         \
                  a1 = fmaf(inv_, (float)vj1_##S, a1);                         \
                  a2 = fmaf(inv_, (float)vj2_##S, a2); }                       \
    else if (g == 1) { a0 += inv_; }                                           \
    else { a0 = fmaf(inv_, unitL[3 * rv_ + 0], a0);                            \
           a1 = fmaf(inv_, unitL[3 * rv_ + 1], a1);                            \
           a2 = fmaf(inv_, unitL[3 * rv_ + 2], a2); }                          \
  } } while (0)

  MK_LOAD(0, 0); MK_LOAD(1, 1); MK_LOAD(2, 2); MK_LOAD(3, 3);
  MK_LOAD(4, 4); MK_LOAD(5, 5); MK_LOAD(6, 6); MK_LOAD(7, 7);
  for (int r = 0; r < cnt; r += 8) {
    MK_PROC(0, r);     MK_LOAD(0, r + 8);
    MK_PROC(1, r + 1); MK_LOAD(1, r + 9);
    MK_PROC(2, r + 2); MK_LOAD(2, r + 10);
    MK_PROC(3, r + 3); MK_LOAD(3, r + 11);
    MK_PROC(4, r + 4); MK_LOAD(4, r + 12);
    MK_PROC(5, r + 5); MK_LOAD(5, r + 13);
    MK_PROC(6, r + 6); MK_LOAD(6, r + 14);
    MK_PROC(7, r + 7); MK_LOAD(7, r + 15);
  }
#undef MK_LOAD
#undef MK_PROC
  // ---- final flush ----
  if (prev_i >= 0) {
    if (g == 1) {
      atomicAdd(s + (size_t)prev_i * 128 + f, a0);
    } else {
      float* vb = v + (size_t)prev_i * 384 + f;
      atomicAdd(vb, a0);
      atomicAdd(vb + 128, a1);
      atomicAdd(vb + 256, a2);
    }
  }
}

// ---------------- s_stack = [s, ||v_v||] (f16 out) ----------------
__global__ __launch_bounds__(256) void stack_kernel(
    const float* __restrict__ s, const float* __restrict__ v_v,
    f16* __restrict__ s_stack, int N)
{
  int idx = blockIdx.x * 256 + threadIdx.x;
  if (idx >= N * 128) return;
  int n = idx >> 7, g = idx & 127;
  float a = v_v[(size_t)n * 384 + g];
  float b = v_v[(size_t)n * 384 + 128 + g];
  float c = v_v[(size_t)n * 384 + 256 + g];
  s_stack[(size_t)n * 256 + g] = (f16)s[idx];
  s_stack[(size_t)n * 256 + 128 + g] = (f16)sqrtf(a * a + b * b + c * c + EPS_F);
}

// ---------------- gated update of s, v (+ f16 mirrors for next-layer reads) ----------------
__global__ __launch_bounds__(256) void apply_kernel(
    float* __restrict__ s, f16* __restrict__ s_h,
    float* __restrict__ v, f16* __restrict__ v_h,
    const float* __restrict__ u_v, const float* __restrict__ v_v,
    const float* __restrict__ sp, int N)
{
  int idx = blockIdx.x * 256 + threadIdx.x;
  if (idx >= N * 128) return;
  int n = idx >> 7, g = idx & 127;
  float sp0 = sp[(size_t)n * 384 + g];
  float sp1 = sp[(size_t)n * 384 + 128 + g];
  float sp2 = sp[(size_t)n * 384 + 256 + g];
  float dot = 0.f;
#pragma unroll
  for (int c = 0; c < 3; ++c) {
    size_t o = (size_t)n * 384 + c * 128 + g;
    float uv = u_v[o];
    float vn = fmaf(uv, sp0, v[o]);
    v[o] = vn;
    v_h[o] = (f16)vn;
    dot = fmaf(uv, v_v[o], dot);
  }
  float sn = s[idx] + dot * sp1 + sp2;
  s[idx] = sn;
  s_h[idx] = (f16)sn;
}

// ---------------- fused f16 MFMA readout (unsorted edges; register-prefetched gathers) ----------------
__global__ __launch_bounds__(256) void readout_gemm_kernel(
    const int* __restrict__ nbr, const float* __restrict__ xyz,
    const f16* __restrict__ s_h, const f16* __restrict__ w1t,
    const float* __restrict__ b1, const float* __restrict__ w2,
    const float* __restrict__ b2, float* __restrict__ out, int E)
{
  __shared__ f16 As[64][40];
  __shared__ f16 Bs[64][40];
  __shared__ float red[2][64];
  __shared__ int ijc[64][2];
  int t = threadIdx.x;
  int wave = t >> 6, lane = t & 63;
  int rw = wave & 1, cw = wave >> 1;
  int lr = lane & 15, quad = lane >> 4;
  int e0b = blockIdx.x * 64;
  if (t < 64) {
    int e = e0b + t;
    if (e < E) { ijc[t][0] = nbr[2 * e]; ijc[t][1] = nbr[2 * e + 1]; }
    else { ijc[t][0] = 0; ijc[t][1] = 0; }
  }
  __syncthreads();
  int m = t >> 2;             // one row (edge) per thread
  int c8 = (t & 3) * 8;       // 8 features within 32-k window
  int im = ijc[m][0], jm = ijc[m][1];
  bool okm = (e0b + m) < E;
  // prefetch all 8 row-segments (4 windows x i/j) - independent loads in flight
  f16x8 xa[4], ya[4];
  if (okm) {
#pragma unroll
    for (int w = 0; w < 4; ++w) {
      xa[w] = *(const f16x8*)(s_h + (size_t)im * 128 + w * 32 + c8);
      ya[w] = *(const f16x8*)(s_h + (size_t)jm * 128 + w * 32 + c8);
    }
  } else {
#pragma unroll
    for (int w = 0; w < 4; ++w)
      for (int q = 0; q < 8; ++q) { xa[w][q] = (f16)0.0f; ya[w][q] = (f16)0.0f; }
  }
  floatx4 acc[2][2] = {};
#pragma unroll
  for (int w = 0; w < 4; ++w) {
    *(f16x8*)&As[m][c8] = xa[w] + ya[w];
    {
      int sm = t >> 2, sk = (t & 3) * 8;
      *(f16x8*)&Bs[sm][sk] = *(const f16x8*)(w1t + (size_t)sm * 128 + w * 32 + sk);
    }
    __syncthreads();
    f16x8 af[2], bfr[2];
#pragma unroll
    for (int tr = 0; tr < 2; ++tr)
      af[tr] = *(const f16x8*)&As[rw * 32 + tr * 16 + lr][quad * 8];
#pragma unroll
    for (int tc = 0; tc < 2; ++tc)
      bfr[tc] = *(const f16x8*)&Bs[cw * 32 + tc * 16 + lr][quad * 8];
#pragma unroll
    for (int tr = 0; tr < 2; ++tr)
#pragma unroll
      for (int tc = 0; tc < 2; ++tc)
        acc[tr][tc] = __builtin_amdgcn_mfma_f32_16x16x32_f16(af[tr], bfr[tc], acc[tr][tc], 0, 0, 0);
    __syncthreads();
  }
  float b1v[2], w2v[2];
#pragma unroll
  for (int tc = 0; tc < 2; ++tc) {
    int col = cw * 32 + tc * 16 + lr;
    b1v[tc] = b1[col];
    w2v[tc] = w2[col];
  }
#pragma unroll
  for (int tr = 0; tr < 2; ++tr) {
#pragma unroll
    for (int r = 0; r < 4; ++r) {
      float p = 0.f;
#pragma unroll
      for (int tc = 0; tc < 2; ++tc)
        p += silu_f(acc[tr][tc][r] + b1v[tc]) * w2v[tc];
#pragma unroll
      for (int ofs = 1; ofs < 16; ofs <<= 1) p += __shfl_xor(p, ofs, 64);
      if (lr == 0) red[cw][rw * 32 + tr * 16 + quad * 4 + r] = p;
    }
  }
  __syncthreads();
  if (t < 64) {
    int e = e0b + t;
    if (e < E) {
      float fs = red[0][t] + red[1][t] + b2[0];
      int i = ijc[t][0], j = ijc[t][1];
      float dx = xyz[3 * i + 0] - xyz[3 * j + 0];
      float dy = xyz[3 * i + 1] - xyz[3 * j + 1];
      float dz = xyz[3 * i + 2] - xyz[3 * j + 2];
      float dis = sqrtf(dx * dx + dy * dy + dz * dz);  // no EPS here (matches ref)
      float sc = fs / dis;
      float fx = sc * dx, fy = sc * dy, fz = sc * dz;
      atomicAdd(out + (size_t)i * 3 + 0, fx);
      atomicAdd(out + (size_t)i * 3 + 1, fy);
      atomicAdd(out + (size_t)i * 3 + 2, fz);
      atomicAdd(out + (size_t)j * 3 + 0, -fx);
      atomicAdd(out + (size_t)j * 3 + 1, -fy);
      atomicAdd(out + (size_t)j * 3 + 2, -fz);
    }
  }
}

extern "C" void kernel_launch(void* const* d_in, const int* in_sizes, int n_in,
                              void* d_out, int out_size, void* d_ws, size_t ws_size,
                              hipStream_t stream) {
  const float* xyz    = (const float*)d_in[0];
  const int*   z      = (const int*)d_in[1];
  const int*   nbr    = (const int*)d_in[2];
  const float* embed  = (const float*)d_in[3];
  const float* msg_w1 = (const float*)d_in[4];
  const float* msg_b1 = (const float*)d_in[5];
  const float* msg_w2 = (const float*)d_in[6];
  const float* msg_b2 = (const float*)d_in[7];
  const float* dist_w = (const float*)d_in[8];
  const float* dist_b = (const float*)d_in[9];
  const float* upd_u  = (const float*)d_in[10];
  const float* upd_v  = (const float*)d_in[11];
  const float* upd_w1 = (const float*)d_in[12];
  const float* upd_b1 = (const float*)d_in[13];
  const float* upd_w2 = (const float*)d_in[14];
  const float* upd_b2 = (const float*)d_in[15];
  const float* ero_w1 = (const float*)d_in[16];
  const float* ero_b1 = (const float*)d_in[17];
  const float* ero_w2 = (const float*)d_in[18];
  const float* ero_b2 = (const float*)d_in[19];

  const int N = in_sizes[1];      // 10000
  const int E = in_sizes[2] / 2;  // 160000
  const int L = 3;

  char* ws = (char*)d_ws;
  size_t off = 0;
  auto alloc = [&](size_t bytes) -> void* {
    void* p = ws + off;
    off += (bytes + 255) & ~(size_t)255;
    return p;
  };
  float* unit_s = (float*)alloc((size_t)E * 3 * 4);
  f16*   rbf_h  = (f16*)alloc((size_t)E * 32 * 2);
  int2*  ij_s   = (int2*)alloc((size_t)E * 8);
  int*   order  = (int*)alloc((size_t)E * 4);
  float* s      = (float*)alloc((size_t)N * 128 * 4);
  f16*   s_h    = (f16*)alloc((size_t)N * 128 * 2);
  float* vA     = (float*)alloc((size_t)N * 384 * 4);
  f16*   vhA    = (f16*)alloc((size_t)N * 384 * 2);
  f16*   phi_h  = (f16*)alloc((size_t)N * 384 * 2);
  f16*   w1t    = (f16*)alloc((size_t)64 * 128 * 2);
  f16*   dwf    = (f16*)alloc((size_t)3 * 24 * 64 * 8 * 2);
  int*   histx  = (int*)alloc((size_t)(N + 1) * 4);
  int*   startp = (int*)alloc((size_t)(N + 1) * 4);
  int*   cursor = (int*)alloc((size_t)N * 4);
  float* u_v    = (float*)alloc((size_t)N * 384 * 4);
  float* v_v    = (float*)alloc((size_t)N * 384 * 4);
  float* sp     = (float*)alloc((size_t)N * 384 * 4);
  f16*   sstk_h = (f16*)alloc((size_t)N * 256 * 2);
  f16*   h_h    = (f16*)alloc((size_t)N * 128 * 2);

  auto cdiv = [](int a, int b) { return (a + b - 1) / b; };

  // ---- setup: deterministic CSR + weight pre-pack ----
  hipMemsetAsync(vA, 0, (size_t)N * 384 * 4, stream);
  hipMemsetAsync(vhA, 0, (size_t)N * 384 * 2, stream);
  hipMemsetAsync(histx, 0, (size_t)(N + 1) * 4, stream);
  hist_kernel<<<cdiv(E, 256), 256, 0, stream>>>(nbr, histx, E);
  scan_kernel<<<1, 1024, 0, stream>>>(histx, startp, cursor, N);
  scatter_id_kernel<<<cdiv(E, 256), 256, 0, stream>>>(nbr, cursor, order, E);
  segsort_kernel<<<cdiv(N, 4), 256, 0, stream>>>(order, startp, N);
  geom_fill_kernel<<<cdiv(E, 256), 256, 0, stream>>>(
      order, nbr, xyz, ij_s, unit_s, rbf_h, E);
  embed_kernel<<<cdiv(N * 128, 256), 256, 0, stream>>>(z, embed, s, s_h, N);
  w1t_kernel<<<cdiv(64 * 128, 256), 256, 0, stream>>>(ero_w1, w1t);
  dwfrag_kernel<<<cdiv(3 * 24 * 64 * 8, 256), 256, 0, stream>>>(dist_w, dist_b, dwf);

  for (int l = 0; l < L; ++l) {
    // phi = silu(s @ msg_w1 + b1) @ msg_w2 + b2  -> f16 (A read from f16 mirror)
    gemm_kernel<true, 1, true><<<dim3(cdiv(N, 64), 2), 256, 0, stream>>>(
        s_h, msg_w1 + (size_t)l * 128 * 128, msg_b1 + (size_t)l * 128, nullptr, h_h, N, 128, 128);
    gemm_kernel<false, 1, true><<<dim3(cdiv(N, 64), 6), 256, 0, stream>>>(
        h_h, msg_w2 + (size_t)l * 128 * 384, msg_b2 + (size_t)l * 384, nullptr, phi_h, N, 384, 128);
    // MFMA-ws message; atomic flush into s / v (in place)
    message_kernel<<<cdiv(E, MEPB), 384, 0, stream>>>(
        ij_s, unit_s, rbf_h, dwf + (size_t)l * 24 * 64 * 8,
        phi_h, vhA, s, vA, E);
    // update block
    gemm_dual_kernel<<<dim3(cdiv(N * 3, 64), 2), 256, 0, stream>>>(
        vA, upd_u + (size_t)l * 128 * 128, upd_v + (size_t)l * 128 * 128,
        u_v, v_v, N * 3, 128, 128);
    stack_kernel<<<cdiv(N * 128, 256), 256, 0, stream>>>(s, v_v, sstk_h, N);
    gemm_kernel<true, 1, true><<<dim3(cdiv(N, 64), 2), 256, 0, stream>>>(
        sstk_h, upd_w1 + (size_t)l * 256 * 128, upd_b1 + (size_t)l * 128, nullptr, h_h, N, 128, 256);
    gemm_kernel<false, 0, true><<<dim3(cdiv(N, 64), 6), 256, 0, stream>>>(
        h_h, upd_w2 + (size_t)l * 128 * 384, upd_b2 + (size_t)l * 384, nullptr, sp, N, 384, 128);
    apply_kernel<<<cdiv(N * 128, 256), 256, 0, stream>>>(
        s, s_h, vA, vhA, u_v, v_v, sp, N);
  }

  // fused f16 MFMA readout (unsorted edges, register-prefetched gathers)
  hipMemsetAsync(d_out, 0, (size_t)out_size * 4, stream);
  readout_gemm_kernel<<<cdiv(E, 64), 256, 0, stream>>>(
      nbr, xyz, s_h, w1t, ero_b1, ero_w2, ero_b2, (float*)d_out, E);
}